// Round 1
// baseline (5505.891 us; speedup 1.0000x reference)
//
#include <hip/hip_runtime.h>

typedef __attribute__((ext_vector_type(8))) short short8;
typedef __attribute__((ext_vector_type(4))) float floatx4;

#define T_SEQ 512
#define NB 64

__device__ __forceinline__ float bf2f(unsigned short u) {
    union { unsigned int i; float f; } c; c.i = ((unsigned int)u) << 16; return c.f;
}
__device__ __forceinline__ unsigned short f2bf(float f) {
    union { float f; unsigned int i; } c; c.f = f;
    unsigned int u = c.i;
    return (unsigned short)((u + 0x7FFFu + ((u >> 16) & 1u)) >> 16);
}
__device__ __forceinline__ float sigm(float x) { return 1.f / (1.f + __expf(-x)); }
__device__ __forceinline__ float tanh_(float x) { return 2.f / (1.f + __expf(-2.f * x)) - 1.f; }

__device__ __forceinline__ void glds16(const void* g, void* l) {
    __builtin_amdgcn_global_load_lds((const __attribute__((address_space(1))) unsigned int*)g,
                                     (__attribute__((address_space(3))) unsigned int*)l, 16, 0, 0);
}

// ---------------- cast weights to bf16 (w_ih_f | w_ih_b | w_hh_f | w_hh_b | w_fc) ----------------
__global__ void k_cast_weights(const float* __restrict__ wihf, const float* __restrict__ wihb,
                               const float* __restrict__ whhf, const float* __restrict__ whhb,
                               const float* __restrict__ wfc, unsigned short* __restrict__ dst) {
    int i = blockIdx.x * 256 + threadIdx.x;
    if (i >= 1064960) return;
    float v;
    if (i < 262144) v = wihf[i];
    else if (i < 524288) v = wihb[i - 262144];
    else if (i < 786432) v = whhf[i - 524288];
    else if (i < 1048576) v = whhb[i - 786432];
    else v = wfc[i - 1048576];
    dst[i] = f2bf(v);
}

// ---------------- embedding gather -> e_t[t*64+b][256] bf16 ----------------
__global__ void k_gather(const int* __restrict__ x, const float* __restrict__ emb,
                         unsigned short* __restrict__ et) {
    int id = blockIdx.x * 256 + threadIdx.x;   // 1,048,576 total
    int m = id >> 5, fi = (id & 31) << 3;
    int b = m & 63, t = m >> 6;
    int v = x[b * 512 + t];
    const float4* s = (const float4*)(emb + ((size_t)v << 8) + fi);
    float4 a = s[0], q = s[1];
    uint4 o;
    o.x = (unsigned)f2bf(a.x) | ((unsigned)f2bf(a.y) << 16);
    o.y = (unsigned)f2bf(a.z) | ((unsigned)f2bf(a.w) << 16);
    o.z = (unsigned)f2bf(q.x) | ((unsigned)f2bf(q.y) << 16);
    o.w = (unsigned)f2bf(q.z) | ((unsigned)f2bf(q.w) << 16);
    *(uint4*)(et + ((size_t)m << 8) + fi) = o;
}

// ---------------- gx = e @ w_ih.T + b, both dirs (N=2048), output bf16 [d][t][b][1024] ----------------
__global__ __launch_bounds__(256, 2) void k_gx(const unsigned short* __restrict__ et,
                                               const unsigned short* __restrict__ wcat,
                                               const float* __restrict__ bfv, const float* __restrict__ bbv,
                                               unsigned short* __restrict__ gx) {
    __shared__ unsigned short As[4096];
    __shared__ unsigned short Bs[4096];
    const int tid = threadIdx.x;
    const int w = tid >> 6, l = tid & 63, quad = l >> 4, col = l & 15;
    const size_t m0 = (size_t)blockIdx.x * 128, n0 = (size_t)blockIdx.y * 128;
    floatx4 C[4][4];
    #pragma unroll
    for (int i = 0; i < 4; ++i)
        #pragma unroll
        for (int j = 0; j < 4; ++j) C[i][j] = (floatx4){0.f, 0.f, 0.f, 0.f};
    const int srow = tid >> 2, scol = (tid & 3) * 16;
    for (int it = 0; it < 8; ++it) {
        const char* ga = (const char*)et + (m0 + srow) * 512 + it * 64 + scol;
        const char* gb = (const char*)wcat + (n0 + srow) * 512 + it * 64 + scol;
        glds16(ga,             (char*)As + w * 1024);
        glds16(ga + 64 * 512,  (char*)As + 4096 + w * 1024);
        glds16(gb,             (char*)Bs + w * 1024);
        glds16(gb + 64 * 512,  (char*)Bs + 4096 + w * 1024);
        __syncthreads();
        short8 Af[4], Bf[4];
        #pragma unroll
        for (int i = 0; i < 4; ++i) {
            Af[i] = *(const short8*)(As + (((w & 1) * 64 + i * 16 + col) * 32 + quad * 8));
            Bf[i] = *(const short8*)(Bs + (((w >> 1) * 64 + i * 16 + col) * 32 + quad * 8));
        }
        #pragma unroll
        for (int i = 0; i < 4; ++i)
            #pragma unroll
            for (int j = 0; j < 4; ++j)
                C[i][j] = __builtin_amdgcn_mfma_f32_16x16x32_bf16(Af[i], Bf[j], C[i][j], 0, 0, 0);
        __syncthreads();
    }
    const int mw = (w & 1) * 64, nw = (w >> 1) * 64;
    #pragma unroll
    for (int j = 0; j < 4; ++j) {
        int n = (int)n0 + nw + j * 16 + col;
        float bias = (n < 1024) ? bfv[n] : bbv[n - 1024];
        size_t dbase = (size_t)(n >> 10) * 33554432 + (size_t)(n & 1023);
        #pragma unroll
        for (int i = 0; i < 4; ++i)
            #pragma unroll
            for (int r = 0; r < 4; ++r) {
                size_t m = m0 + mw + i * 16 + quad * 4 + r;
                gx[dbase + m * 1024] = f2bf(C[i][j][r] + bias);
            }
    }
}

// ---------------- LSTM recurrence: 8 wgs = 2 dirs x 4 batch-groups of 16 ----------------
// z(64x... per wg 16x1024) = h @ W^T + gx ; gates i,f,g,o ; h -> LDS (next step) + global hcat
__global__ __launch_bounds__(512, 2) void k_lstm(const unsigned short* __restrict__ whh_all,
                                                 const unsigned short* __restrict__ gx_all,
                                                 unsigned short* __restrict__ hcat) {
    const int d = blockIdx.x >> 2, bg = blockIdx.x & 3;
    const int tid = threadIdx.x, w = tid >> 6, l = tid & 63, quad = l >> 4, col = l & 15;
    const unsigned short* W = whh_all + (size_t)d * 262144;
    const unsigned short* G = gx_all + (size_t)d * 33554432;
    __shared__ short8 wlds[8][6][64];        // 48 KB: per-wave kt=4, a<6 fragments
    __shared__ unsigned short hld[16][264];  // h[batch][unit] bf16, padded pitch

    // A-fragment: lane holds W[16*mt + col][kt*32 + quad*8 + j], mt(a) = 2w + (a&1) + 16*(a>>1)
    short8 Wreg[4][8];   // kt = 0..3 resident
    #pragma unroll
    for (int kt = 0; kt < 4; ++kt)
        #pragma unroll
        for (int a = 0; a < 8; ++a) {
            int mt = 2 * w + (a & 1) + 16 * (a >> 1);
            Wreg[kt][a] = *(const short8*)(W + (size_t)((16 * mt + col) * 256 + kt * 32 + quad * 8));
        }
    #pragma unroll
    for (int a = 0; a < 6; ++a) {
        int mt = 2 * w + (a & 1) + 16 * (a >> 1);
        wlds[w][a][l] = *(const short8*)(W + (size_t)((16 * mt + col) * 256 + 4 * 32 + quad * 8));
    }
    for (int idx = tid; idx < 16 * 264; idx += 512) (&hld[0][0])[idx] = 0;

    const unsigned short* Wo = W;  // opaque copy: defeat LICM on streamed loads
    short8 Ws[8];
    #pragma unroll
    for (int a = 0; a < 8; ++a) {
        int mt = 2 * w + (a & 1) + 16 * (a >> 1);
        Ws[a] = *(const short8*)(W + (size_t)((16 * mt + col) * 256 + 7 * 32 + quad * 8));
    }
    float cst[2][4] = {{0.f, 0.f, 0.f, 0.f}, {0.f, 0.f, 0.f, 0.f}};
    const int bb = bg * 16 + col;
    __syncthreads();

    #pragma clang loop unroll(disable)
    for (int step = 0; step < 512; ++step) {
        asm volatile("" : "+v"(Wo));
        const int t = d ? (511 - step) : step;
        uint2 gxb[8];
        #pragma unroll
        for (int a = 0; a < 8; ++a) {
            int mt = 2 * w + (a & 1) + 16 * (a >> 1);
            gxb[a] = *(const uint2*)(G + ((size_t)(t * 64 + bb) * 1024 + 16 * mt + quad * 4));
        }
        floatx4 C[8];
        #pragma unroll
        for (int a = 0; a < 8; ++a) C[a] = (floatx4){0.f, 0.f, 0.f, 0.f};
        short8 Bf;
        // kt = 7 (streamed, preloaded)
        Bf = *(const short8*)(&hld[col][7 * 32 + quad * 8]);
        #pragma unroll
        for (int a = 0; a < 8; ++a) C[a] = __builtin_amdgcn_mfma_f32_16x16x32_bf16(Ws[a], Bf, C[a], 0, 0, 0);
        #pragma unroll
        for (int a = 0; a < 8; ++a) {
            int mt = 2 * w + (a & 1) + 16 * (a >> 1);
            Ws[a] = *(const short8*)(Wo + (size_t)((16 * mt + col) * 256 + 6 * 32 + quad * 8));
        }
        // kt = 6
        Bf = *(const short8*)(&hld[col][6 * 32 + quad * 8]);
        #pragma unroll
        for (int a = 0; a < 8; ++a) C[a] = __builtin_amdgcn_mfma_f32_16x16x32_bf16(Ws[a], Bf, C[a], 0, 0, 0);
        #pragma unroll
        for (int a = 0; a < 8; ++a) {
            int mt = 2 * w + (a & 1) + 16 * (a >> 1);
            Ws[a] = *(const short8*)(Wo + (size_t)((16 * mt + col) * 256 + 5 * 32 + quad * 8));
        }
        // kt = 5
        Bf = *(const short8*)(&hld[col][5 * 32 + quad * 8]);
        #pragma unroll
        for (int a = 0; a < 8; ++a) C[a] = __builtin_amdgcn_mfma_f32_16x16x32_bf16(Ws[a], Bf, C[a], 0, 0, 0);
        {
            int mt6 = 2 * w + 0 + 16 * 3, mt7 = 2 * w + 1 + 16 * 3;
            Ws[6] = *(const short8*)(Wo + (size_t)((16 * mt6 + col) * 256 + 4 * 32 + quad * 8));
            Ws[7] = *(const short8*)(Wo + (size_t)((16 * mt7 + col) * 256 + 4 * 32 + quad * 8));
        }
        // kt = 4 (LDS a<6, stream tail a=6,7)
        Bf = *(const short8*)(&hld[col][4 * 32 + quad * 8]);
        #pragma unroll
        for (int a = 0; a < 6; ++a) C[a] = __builtin_amdgcn_mfma_f32_16x16x32_bf16(wlds[w][a][l], Bf, C[a], 0, 0, 0);
        C[6] = __builtin_amdgcn_mfma_f32_16x16x32_bf16(Ws[6], Bf, C[6], 0, 0, 0);
        C[7] = __builtin_amdgcn_mfma_f32_16x16x32_bf16(Ws[7], Bf, C[7], 0, 0, 0);
        // refill kt=7 for next step (in flight across rest of step)
        #pragma unroll
        for (int a = 0; a < 8; ++a) {
            int mt = 2 * w + (a & 1) + 16 * (a >> 1);
            Ws[a] = *(const short8*)(Wo + (size_t)((16 * mt + col) * 256 + 7 * 32 + quad * 8));
        }
        // kt = 3..0 from registers
        #pragma unroll
        for (int kk = 0; kk < 4; ++kk) {
            int kt = 3 - kk;
            Bf = *(const short8*)(&hld[col][kt * 32 + quad * 8]);
            #pragma unroll
            for (int a = 0; a < 8; ++a) C[a] = __builtin_amdgcn_mfma_f32_16x16x32_bf16(Wreg[kt][a], Bf, C[a], 0, 0, 0);
        }
        // gate nonlinearities + state update (lane-local: i/f/g/o tiles aligned by construction)
        uint2 hpk[2];
        #pragma unroll
        for (int p = 0; p < 2; ++p) {
            unsigned short hh[4];
            #pragma unroll
            for (int r = 0; r < 4; ++r) {
                float gi = bf2f((unsigned short)(((r & 2) ? gxb[0 + p].y : gxb[0 + p].x) >> ((r & 1) * 16)));
                float gf = bf2f((unsigned short)(((r & 2) ? gxb[2 + p].y : gxb[2 + p].x) >> ((r & 1) * 16)));
                float gg = bf2f((unsigned short)(((r & 2) ? gxb[4 + p].y : gxb[4 + p].x) >> ((r & 1) * 16)));
                float go = bf2f((unsigned short)(((r & 2) ? gxb[6 + p].y : gxb[6 + p].x) >> ((r & 1) * 16)));
                float zi = C[0 + p][r] + gi;
                float zf = C[2 + p][r] + gf;
                float zg = C[4 + p][r] + gg;
                float zo = C[6 + p][r] + go;
                float cc = sigm(zf) * cst[p][r] + sigm(zi) * tanh_(zg);
                cst[p][r] = cc;
                hh[r] = f2bf(sigm(zo) * tanh_(cc));
            }
            hpk[p].x = (unsigned)hh[0] | ((unsigned)hh[1] << 16);
            hpk[p].y = (unsigned)hh[2] | ((unsigned)hh[3] << 16);
            int j0 = 16 * (2 * w + p) + quad * 4;
            *(uint2*)(hcat + ((size_t)(t * 64 + bb) * 512 + d * 256 + j0)) = hpk[p];
        }
        __syncthreads();
        #pragma unroll
        for (int p = 0; p < 2; ++p) {
            int j0 = 16 * (2 * w + p) + quad * 4;
            *(uint2*)(&hld[col][j0]) = hpk[p];
        }
        __syncthreads();
    }
}

// ---------------- scores = hcat @ w_fc.T + b_fc, fp32 [t][b][32] ----------------
__global__ __launch_bounds__(256, 4) void k_scores(const unsigned short* __restrict__ hcat,
                                                   const unsigned short* __restrict__ wfc,
                                                   const float* __restrict__ bfc,
                                                   float* __restrict__ sc) {
    const int tid = threadIdx.x, w = tid >> 6, l = tid & 63, quad = l >> 4, col = l & 15;
    const int m0 = blockIdx.x * 64 + w * 16;
    floatx4 C0 = (floatx4){0.f, 0.f, 0.f, 0.f}, C1 = C0;
    #pragma unroll
    for (int kt = 0; kt < 16; ++kt) {
        short8 A  = *(const short8*)(hcat + (size_t)(m0 + col) * 512 + kt * 32 + quad * 8);
        short8 B0 = *(const short8*)(wfc + (size_t)col * 512 + kt * 32 + quad * 8);
        short8 B1 = *(const short8*)(wfc + (size_t)(16 + col) * 512 + kt * 32 + quad * 8);
        C0 = __builtin_amdgcn_mfma_f32_16x16x32_bf16(A, B0, C0, 0, 0, 0);
        C1 = __builtin_amdgcn_mfma_f32_16x16x32_bf16(A, B1, C1, 0, 0, 0);
    }
    float b0 = bfc[col], b1 = bfc[16 + col];
    #pragma unroll
    for (int r = 0; r < 4; ++r) {
        int m = m0 + quad * 4 + r;
        sc[(size_t)m * 32 + col] = C0[r] + b0;
        sc[(size_t)m * 32 + 16 + col] = C1[r] + b1;
    }
}

// ---------------- CRF: true path score + forward algorithm, loss += total - true ----------------
__global__ __launch_bounds__(1024, 1) void k_crf(const float* __restrict__ sc, const int* __restrict__ tags,
                                                 const int* __restrict__ mask, const float* __restrict__ tr,
                                                 float* __restrict__ out) {
    __shared__ float Tm[32][33];
    __shared__ float alpha[32];
    __shared__ float trueb;
    const int b = blockIdx.x, tid = threadIdx.x;
    { int i = tid >> 5, j = tid & 31; Tm[i][j] = tr[tid]; }
    __syncthreads();
    if (tid < 64) {
        float acc = 0.f; int cnt = 0;
        for (int t = tid; t < 512; t += 64) cnt += mask[b * 512 + t];
        for (int t = tid + 1; t < 512; t += 64) {
            if (mask[b * 512 + t]) {
                int tg = tags[b * 512 + t], tp = tags[b * 512 + t - 1];
                acc += Tm[tp][tg] + sc[((size_t)t * 64 + b) * 32 + tg];
            }
        }
        #pragma unroll
        for (int m = 1; m < 64; m <<= 1) { acc += __shfl_xor(acc, m); cnt += __shfl_xor(cnt, m); }
        if (tid == 0) {
            int tg0 = tags[b * 512];
            float first = Tm[30][tg0] + sc[(size_t)b * 32 + tg0];
            int lt = tags[b * 512 + cnt - 1];
            trueb = first + acc + Tm[lt][31];
        }
    }
    if (tid < 32) alpha[tid] = Tm[30][tid] + sc[(size_t)b * 32 + tid];
    __syncthreads();
    const int j = tid >> 5, i = tid & 31;
    #pragma clang loop unroll(disable)
    for (int t = 1; t < 512; ++t) {
        float v = alpha[i] + Tm[i][j];
        float mx = v;
        #pragma unroll
        for (int m = 1; m < 32; m <<= 1) mx = fmaxf(mx, __shfl_xor(mx, m));
        float e = __expf(v - mx);
        #pragma unroll
        for (int m = 1; m < 32; m <<= 1) e += __shfl_xor(e, m);
        float nv = mx + __logf(e) + sc[((size_t)t * 64 + b) * 32 + j];
        int mk = mask[b * 512 + t];
        __syncthreads();
        if (mk && i == 0) alpha[j] = nv;
        __syncthreads();
    }
    if (tid < 32) {
        float v = alpha[tid] + Tm[tid][31];
        float mx = v;
        #pragma unroll
        for (int m = 1; m < 32; m <<= 1) mx = fmaxf(mx, __shfl_xor(mx, m));
        float e = __expf(v - mx);
        #pragma unroll
        for (int m = 1; m < 32; m <<= 1) e += __shfl_xor(e, m);
        if (tid == 0) atomicAdd(out, mx + __logf(e) - trueb);
    }
}

extern "C" void kernel_launch(void* const* d_in, const int* in_sizes, int n_in,
                              void* d_out, int out_size, void* d_ws, size_t ws_size,
                              hipStream_t stream) {
    const int* x      = (const int*)d_in[0];
    const int* tags   = (const int*)d_in[1];
    const int* mask   = (const int*)d_in[2];
    const float* emb  = (const float*)d_in[3];
    const float* wihf = (const float*)d_in[4];
    const float* whhf = (const float*)d_in[5];
    const float* bf_  = (const float*)d_in[6];
    const float* wihb = (const float*)d_in[7];
    const float* whhb = (const float*)d_in[8];
    const float* bb_  = (const float*)d_in[9];
    const float* wfc  = (const float*)d_in[10];
    const float* bfc  = (const float*)d_in[11];
    const float* tr   = (const float*)d_in[12];

    char* ws = (char*)d_ws;
    unsigned short* et   = (unsigned short*)(ws);                 // 16,777,216 B
    unsigned short* wbf  = (unsigned short*)(ws + 16777216);      //  2,129,920 B (wih cat | whh f,b | wfc)
    unsigned short* gx   = (unsigned short*)(ws + 18907136);      // 134,217,728 B
    unsigned short* hcat = (unsigned short*)(ws + 153124864);     // 33,554,432 B
    float* sc            = (float*)(ws + 186679296);              //  4,194,304 B

    hipMemsetAsync(d_out, 0, sizeof(float), stream);
    k_cast_weights<<<4160, 256, 0, stream>>>(wihf, wihb, whhf, whhb, wfc, wbf);
    k_gather<<<4096, 256, 0, stream>>>(x, emb, et);
    dim3 g2(256, 16);
    k_gx<<<g2, 256, 0, stream>>>(et, wbf, bf_, bb_, gx);
    k_lstm<<<8, 512, 0, stream>>>(wbf + 524288, gx, hcat);
    k_scores<<<512, 256, 0, stream>>>(hcat, wbf + 1048576, bfc, sc);
    k_crf<<<64, 1024, 0, stream>>>(sc, tags, mask, tr, (float*)d_out);
}

// Round 2
// 2727.712 us; speedup vs baseline: 2.0185x; 2.0185x over previous
//
#include <hip/hip_runtime.h>

typedef __attribute__((ext_vector_type(8))) short short8;
typedef __attribute__((ext_vector_type(4))) float floatx4;

__device__ __forceinline__ float bf2f(unsigned short u) {
    union { unsigned int i; float f; } c; c.i = ((unsigned int)u) << 16; return c.f;
}
__device__ __forceinline__ unsigned short f2bf(float f) {
    union { float f; unsigned int i; } c; c.f = f;
    unsigned int u = c.i;
    return (unsigned short)((u + 0x7FFFu + ((u >> 16) & 1u)) >> 16);
}
__device__ __forceinline__ float sigm(float x) { return 1.f / (1.f + __expf(-x)); }
__device__ __forceinline__ float tanh_(float x) { return 2.f / (1.f + __expf(-2.f * x)) - 1.f; }

__device__ __forceinline__ void glds16(const void* g, void* l) {
    __builtin_amdgcn_global_load_lds((const __attribute__((address_space(1))) unsigned int*)g,
                                     (__attribute__((address_space(3))) unsigned int*)l, 16, 0, 0);
}

// ---------------- cast weights to bf16 (w_ih_f | w_ih_b | w_fc) ----------------
__global__ void k_cast_weights(const float* __restrict__ wihf, const float* __restrict__ wihb,
                               const float* __restrict__ wfc, unsigned short* __restrict__ dst) {
    int i = blockIdx.x * 256 + threadIdx.x;
    if (i >= 532480) return;
    float v;
    if (i < 262144) v = wihf[i];
    else if (i < 524288) v = wihb[i - 262144];
    else v = wfc[i - 524288];
    dst[i] = f2bf(v);
}

// ---------------- cast w_hh (f|b) to fp8 e4m3 ----------------
__global__ void k_cast_fp8(const float* __restrict__ whhf, const float* __restrict__ whhb,
                           unsigned char* __restrict__ dst) {
    int i = blockIdx.x * 256 + threadIdx.x;   // 262144 threads, 2 elems each
    if (i >= 262144) return;
    int e = i * 2;
    float a = (e < 262144) ? whhf[e] : whhb[e - 262144];
    float b = (e + 1 < 262144) ? whhf[e + 1] : whhb[e + 1 - 262144];
    int p = __builtin_amdgcn_cvt_pk_fp8_f32(a, b, 0, false);
    *(unsigned short*)(dst + e) = (unsigned short)(p & 0xffff);
}

// ---------------- embedding gather -> e_t[t*64+b][256] bf16 ----------------
__global__ void k_gather(const int* __restrict__ x, const float* __restrict__ emb,
                         unsigned short* __restrict__ et) {
    int id = blockIdx.x * 256 + threadIdx.x;   // 1,048,576 total
    int m = id >> 5, fi = (id & 31) << 3;
    int b = m & 63, t = m >> 6;
    int v = x[b * 512 + t];
    const float4* s = (const float4*)(emb + ((size_t)v << 8) + fi);
    float4 a = s[0], q = s[1];
    uint4 o;
    o.x = (unsigned)f2bf(a.x) | ((unsigned)f2bf(a.y) << 16);
    o.y = (unsigned)f2bf(a.z) | ((unsigned)f2bf(a.w) << 16);
    o.z = (unsigned)f2bf(q.x) | ((unsigned)f2bf(q.y) << 16);
    o.w = (unsigned)f2bf(q.z) | ((unsigned)f2bf(q.w) << 16);
    *(uint4*)(et + ((size_t)m << 8) + fi) = o;
}

// ---------------- gx = e @ w_ih.T + b, both dirs (N=2048), output bf16 [d][t][b][1024] ----------------
__global__ __launch_bounds__(256, 2) void k_gx(const unsigned short* __restrict__ et,
                                               const unsigned short* __restrict__ wcat,
                                               const float* __restrict__ bfv, const float* __restrict__ bbv,
                                               unsigned short* __restrict__ gx) {
    __shared__ unsigned short As[4096];
    __shared__ unsigned short Bs[4096];
    const int tid = threadIdx.x;
    const int w = tid >> 6, l = tid & 63, quad = l >> 4, col = l & 15;
    const size_t m0 = (size_t)blockIdx.x * 128, n0 = (size_t)blockIdx.y * 128;
    floatx4 C[4][4];
    #pragma unroll
    for (int i = 0; i < 4; ++i)
        #pragma unroll
        for (int j = 0; j < 4; ++j) C[i][j] = (floatx4){0.f, 0.f, 0.f, 0.f};
    const int srow = tid >> 2, scol = (tid & 3) * 16;
    for (int it = 0; it < 8; ++it) {
        const char* ga = (const char*)et + (m0 + srow) * 512 + it * 64 + scol;
        const char* gb = (const char*)wcat + (n0 + srow) * 512 + it * 64 + scol;
        glds16(ga,             (char*)As + w * 1024);
        glds16(ga + 64 * 512,  (char*)As + 4096 + w * 1024);
        glds16(gb,             (char*)Bs + w * 1024);
        glds16(gb + 64 * 512,  (char*)Bs + 4096 + w * 1024);
        __syncthreads();
        short8 Af[4], Bf[4];
        #pragma unroll
        for (int i = 0; i < 4; ++i) {
            Af[i] = *(const short8*)(As + (((w & 1) * 64 + i * 16 + col) * 32 + quad * 8));
            Bf[i] = *(const short8*)(Bs + (((w >> 1) * 64 + i * 16 + col) * 32 + quad * 8));
        }
        #pragma unroll
        for (int i = 0; i < 4; ++i)
            #pragma unroll
            for (int j = 0; j < 4; ++j)
                C[i][j] = __builtin_amdgcn_mfma_f32_16x16x32_bf16(Af[i], Bf[j], C[i][j], 0, 0, 0);
        __syncthreads();
    }
    const int mw = (w & 1) * 64, nw = (w >> 1) * 64;
    #pragma unroll
    for (int j = 0; j < 4; ++j) {
        int n = (int)n0 + nw + j * 16 + col;
        float bias = (n < 1024) ? bfv[n] : bbv[n - 1024];
        size_t dbase = (size_t)(n >> 10) * 33554432 + (size_t)(n & 1023);
        #pragma unroll
        for (int i = 0; i < 4; ++i)
            #pragma unroll
            for (int r = 0; r < 4; ++r) {
                size_t m = m0 + mw + i * 16 + quad * 4 + r;
                gx[dbase + m * 1024] = f2bf(C[i][j][r] + bias);
            }
    }
}

// ---------------- LSTM recurrence: 8 wgs = 2 dirs x 4 batch-groups of 16 ----------------
// W (fp8) fully register-resident: 64 tiles/wave x 8B = 128 VGPR. h carried fp8 via
// double-buffered LDS, one barrier/step. gx prefetched one half-step ahead.
__global__ __launch_bounds__(512, 2) void k_lstm(const unsigned char* __restrict__ w8_all,
                                                 const unsigned short* __restrict__ gx_all,
                                                 unsigned short* __restrict__ hcat) {
    const int d = blockIdx.x >> 2, bg = blockIdx.x & 3;
    const int tid = threadIdx.x, w = tid >> 6, l = tid & 63, quad = l >> 4, col = l & 15;
    const unsigned char* W = w8_all + (size_t)d * 262144;
    const unsigned short* G = gx_all + (size_t)d * 33554432;
    __shared__ __align__(16) unsigned char hld[2][16][264];

    // A-fragments: lane holds W[16*mt + col][kt*32 + quad*8 + j], j=0..7 (8 bytes)
    long Wr[8][8];   // [kt][a], mt(a) = 2w + (a&1) + 16*(a>>1)
    #pragma unroll
    for (int kt = 0; kt < 8; ++kt)
        #pragma unroll
        for (int a = 0; a < 8; ++a) {
            int mt = 2 * w + (a & 1) + 16 * (a >> 1);
            Wr[kt][a] = *(const long*)(W + (size_t)(16 * mt + col) * 256 + kt * 32 + quad * 8);
        }
    for (int i = tid; i < 2112; i += 512) ((unsigned int*)hld)[i] = 0;

    float cst[2][4] = {{0.f, 0.f, 0.f, 0.f}, {0.f, 0.f, 0.f, 0.f}};
    const int bb = bg * 16 + col;

    uint2 g0[8], g1[8];
    {
        int t0 = d ? 511 : 0;
        #pragma unroll
        for (int a = 0; a < 8; ++a) {
            int mt = 2 * w + (a & 1) + 16 * (a >> 1);
            g0[a] = *(const uint2*)(G + ((size_t)(t0 * 64 + bb) * 1024 + 16 * mt + quad * 4));
        }
    }
    __syncthreads();

    auto body = [&](uint2 (&gc)[8], uint2 (&gn)[8], int cur, int tcur, int tnext) {
        // prefetch next body's gx (HBM latency cover ~1 body)
        #pragma unroll
        for (int a = 0; a < 8; ++a) {
            int mt = 2 * w + (a & 1) + 16 * (a >> 1);
            gn[a] = *(const uint2*)(G + ((size_t)(tnext * 64 + bb) * 1024 + 16 * mt + quad * 4));
        }
        // B-fragments: lane holds h_fp8[batch=col][k = kt*32 + quad*8 + j]
        long Bf[8];
        #pragma unroll
        for (int kt = 0; kt < 8; ++kt)
            Bf[kt] = *(const long*)(&hld[cur][col][kt * 32 + quad * 8]);
        floatx4 C[8];
        #pragma unroll
        for (int a = 0; a < 8; ++a) C[a] = (floatx4){0.f, 0.f, 0.f, 0.f};
        #pragma unroll
        for (int kt = 0; kt < 8; ++kt)
            #pragma unroll
            for (int a = 0; a < 8; ++a)
                C[a] = __builtin_amdgcn_mfma_f32_16x16x32_fp8_fp8(Wr[kt][a], Bf[kt], C[a], 0, 0, 0);
        // gates + state update (lane-local by construction)
        #pragma unroll
        for (int p = 0; p < 2; ++p) {
            float hf[4];
            #pragma unroll
            for (int r = 0; r < 4; ++r) {
                float gi = bf2f((unsigned short)(((r & 2) ? gc[0 + p].y : gc[0 + p].x) >> ((r & 1) * 16)));
                float gf = bf2f((unsigned short)(((r & 2) ? gc[2 + p].y : gc[2 + p].x) >> ((r & 1) * 16)));
                float gg = bf2f((unsigned short)(((r & 2) ? gc[4 + p].y : gc[4 + p].x) >> ((r & 1) * 16)));
                float go = bf2f((unsigned short)(((r & 2) ? gc[6 + p].y : gc[6 + p].x) >> ((r & 1) * 16)));
                float zi = C[0 + p][r] + gi;
                float zf = C[2 + p][r] + gf;
                float zg = C[4 + p][r] + gg;
                float zo = C[6 + p][r] + go;
                float cc = sigm(zf) * cst[p][r] + sigm(zi) * tanh_(zg);
                cst[p][r] = cc;
                hf[r] = sigm(zo) * tanh_(cc);
            }
            int j0 = 16 * (2 * w + p) + quad * 4;
            uint2 hb;
            hb.x = (unsigned)f2bf(hf[0]) | ((unsigned)f2bf(hf[1]) << 16);
            hb.y = (unsigned)f2bf(hf[2]) | ((unsigned)f2bf(hf[3]) << 16);
            *(uint2*)(hcat + ((size_t)(tcur * 64 + bb) * 512 + d * 256 + j0)) = hb;
            int lo = __builtin_amdgcn_cvt_pk_fp8_f32(hf[0], hf[1], 0, false);
            int fu = __builtin_amdgcn_cvt_pk_fp8_f32(hf[2], hf[3], lo, true);
            *(unsigned int*)(&hld[cur ^ 1][col][j0]) = (unsigned int)fu;
        }
        __syncthreads();
    };

    #pragma clang loop unroll(disable)
    for (int step = 0; step < 512; step += 2) {
        int tA = d ? 511 - step : step;
        int tB = d ? 510 - step : step + 1;
        int sC = (step + 2) & 511;
        int tC = d ? 511 - sC : sC;
        body(g0, g1, 0, tA, tB);
        body(g1, g0, 1, tB, tC);
    }
}

// ---------------- scores = hcat @ w_fc.T + b_fc, fp32 [t][b][32] ----------------
__global__ __launch_bounds__(256, 4) void k_scores(const unsigned short* __restrict__ hcat,
                                                   const unsigned short* __restrict__ wfc,
                                                   const float* __restrict__ bfc,
                                                   float* __restrict__ sc) {
    const int tid = threadIdx.x, w = tid >> 6, l = tid & 63, quad = l >> 4, col = l & 15;
    const int m0 = blockIdx.x * 64 + w * 16;
    floatx4 C0 = (floatx4){0.f, 0.f, 0.f, 0.f}, C1 = C0;
    #pragma unroll
    for (int kt = 0; kt < 16; ++kt) {
        short8 A  = *(const short8*)(hcat + (size_t)(m0 + col) * 512 + kt * 32 + quad * 8);
        short8 B0 = *(const short8*)(wfc + (size_t)col * 512 + kt * 32 + quad * 8);
        short8 B1 = *(const short8*)(wfc + (size_t)(16 + col) * 512 + kt * 32 + quad * 8);
        C0 = __builtin_amdgcn_mfma_f32_16x16x32_bf16(A, B0, C0, 0, 0, 0);
        C1 = __builtin_amdgcn_mfma_f32_16x16x32_bf16(A, B1, C1, 0, 0, 0);
    }
    float b0 = bfc[col], b1 = bfc[16 + col];
    #pragma unroll
    for (int r = 0; r < 4; ++r) {
        int m = m0 + quad * 4 + r;
        sc[(size_t)m * 32 + col] = C0[r] + b0;
        sc[(size_t)m * 32 + 16 + col] = C1[r] + b1;
    }
}

// ---------------- CRF: true path score + forward algorithm, loss += total - true ----------------
__global__ __launch_bounds__(1024, 1) void k_crf(const float* __restrict__ sc, const int* __restrict__ tags,
                                                 const int* __restrict__ mask, const float* __restrict__ tr,
                                                 float* __restrict__ out) {
    __shared__ float Tm[32][33];
    __shared__ float alpha[32];
    __shared__ float trueb;
    const int b = blockIdx.x, tid = threadIdx.x;
    { int i = tid >> 5, j = tid & 31; Tm[i][j] = tr[tid]; }
    __syncthreads();
    if (tid < 64) {
        float acc = 0.f; int cnt = 0;
        for (int t = tid; t < 512; t += 64) cnt += mask[b * 512 + t];
        for (int t = tid + 1; t < 512; t += 64) {
            if (mask[b * 512 + t]) {
                int tg = tags[b * 512 + t], tp = tags[b * 512 + t - 1];
                acc += Tm[tp][tg] + sc[((size_t)t * 64 + b) * 32 + tg];
            }
        }
        #pragma unroll
        for (int m = 1; m < 64; m <<= 1) { acc += __shfl_xor(acc, m); cnt += __shfl_xor(cnt, m); }
        if (tid == 0) {
            int tg0 = tags[b * 512];
            float first = Tm[30][tg0] + sc[(size_t)b * 32 + tg0];
            int lt = tags[b * 512 + cnt - 1];
            trueb = first + acc + Tm[lt][31];
        }
    }
    if (tid < 32) alpha[tid] = Tm[30][tid] + sc[(size_t)b * 32 + tid];
    __syncthreads();
    const int j = tid >> 5, i = tid & 31;
    #pragma clang loop unroll(disable)
    for (int t = 1; t < 512; ++t) {
        float v = alpha[i] + Tm[i][j];
        float mx = v;
        #pragma unroll
        for (int m = 1; m < 32; m <<= 1) mx = fmaxf(mx, __shfl_xor(mx, m));
        float e = __expf(v - mx);
        #pragma unroll
        for (int m = 1; m < 32; m <<= 1) e += __shfl_xor(e, m);
        float nv = mx + __logf(e) + sc[((size_t)t * 64 + b) * 32 + j];
        int mk = mask[b * 512 + t];
        __syncthreads();
        if (mk && i == 0) alpha[j] = nv;
        __syncthreads();
    }
    if (tid < 32) {
        float v = alpha[tid] + Tm[tid][31];
        float mx = v;
        #pragma unroll
        for (int m = 1; m < 32; m <<= 1) mx = fmaxf(mx, __shfl_xor(mx, m));
        float e = __expf(v - mx);
        #pragma unroll
        for (int m = 1; m < 32; m <<= 1) e += __shfl_xor(e, m);
        if (tid == 0) atomicAdd(out, mx + __logf(e) - trueb);
    }
}

extern "C" void kernel_launch(void* const* d_in, const int* in_sizes, int n_in,
                              void* d_out, int out_size, void* d_ws, size_t ws_size,
                              hipStream_t stream) {
    const int* x      = (const int*)d_in[0];
    const int* tags   = (const int*)d_in[1];
    const int* mask   = (const int*)d_in[2];
    const float* emb  = (const float*)d_in[3];
    const float* wihf = (const float*)d_in[4];
    const float* whhf = (const float*)d_in[5];
    const float* bf_  = (const float*)d_in[6];
    const float* wihb = (const float*)d_in[7];
    const float* whhb = (const float*)d_in[8];
    const float* bb_  = (const float*)d_in[9];
    const float* wfc  = (const float*)d_in[10];
    const float* bfc  = (const float*)d_in[11];
    const float* tr   = (const float*)d_in[12];

    char* ws = (char*)d_ws;
    unsigned short* et   = (unsigned short*)(ws);                 //  16,777,216 B
    unsigned short* wbf  = (unsigned short*)(ws + 16777216);      //   1,064,960 B (wih f|b cat, then wfc @ elem 524288)
    unsigned char*  w8   = (unsigned char*)(ws + 17842176);      //     524,288 B (whh f|b fp8)
    unsigned short* gx   = (unsigned short*)(ws + 18366464);      // 134,217,728 B
    unsigned short* hcat = (unsigned short*)(ws + 152584192);     //  33,554,432 B
    float* sc            = (float*)(ws + 186138624);              //   4,194,304 B

    hipMemsetAsync(d_out, 0, sizeof(float), stream);
    k_cast_weights<<<2080, 256, 0, stream>>>(wihf, wihb, wfc, wbf);
    k_cast_fp8<<<1024, 256, 0, stream>>>(whhf, whhb, w8);
    k_gather<<<4096, 256, 0, stream>>>(x, emb, et);
    dim3 g2(256, 16);
    k_gx<<<g2, 256, 0, stream>>>(et, wbf, bf_, bb_, gx);
    k_lstm<<<8, 512, 0, stream>>>(w8, gx, hcat);
    k_scores<<<512, 256, 0, stream>>>(hcat, wbf + 524288, bfc, sc);
    k_crf<<<64, 1024, 0, stream>>>(sc, tags, mask, tr, (float*)d_out);
}

// Round 3
// 1969.021 us; speedup vs baseline: 2.7963x; 1.3853x over previous
//
#include <hip/hip_runtime.h>

typedef __attribute__((ext_vector_type(8))) short short8;
typedef __attribute__((ext_vector_type(4))) float floatx4;

__device__ __forceinline__ float bf2f(unsigned short u) {
    union { unsigned int i; float f; } c; c.i = ((unsigned int)u) << 16; return c.f;
}
__device__ __forceinline__ unsigned short f2bf(float f) {
    union { float f; unsigned int i; } c; c.f = f;
    unsigned int u = c.i;
    return (unsigned short)((u + 0x7FFFu + ((u >> 16) & 1u)) >> 16);
}
__device__ __forceinline__ float sigm(float x) { return 1.f / (1.f + __expf(-x)); }
__device__ __forceinline__ float tanh_(float x) { return 2.f / (1.f + __expf(-2.f * x)) - 1.f; }

__device__ __forceinline__ void glds16(const void* g, void* l) {
    __builtin_amdgcn_global_load_lds((const __attribute__((address_space(1))) unsigned int*)g,
                                     (__attribute__((address_space(3))) unsigned int*)l, 16, 0, 0);
}

// ---------------- cast weights to bf16 (w_ih_f | w_ih_b | w_fc) ----------------
__global__ void k_cast_weights(const float* __restrict__ wihf, const float* __restrict__ wihb,
                               const float* __restrict__ wfc, unsigned short* __restrict__ dst) {
    int i = blockIdx.x * 256 + threadIdx.x;
    if (i >= 532480) return;
    float v;
    if (i < 262144) v = wihf[i];
    else if (i < 524288) v = wihb[i - 262144];
    else v = wfc[i - 524288];
    dst[i] = f2bf(v);
}

// ---------------- cast w_hh (f|b) to fp8 e4m3 ----------------
__global__ void k_cast_fp8(const float* __restrict__ whhf, const float* __restrict__ whhb,
                           unsigned char* __restrict__ dst) {
    int i = blockIdx.x * 256 + threadIdx.x;   // 262144 threads, 2 elems each
    if (i >= 262144) return;
    int e = i * 2;
    float a = (e < 262144) ? whhf[e] : whhb[e - 262144];
    float b = (e + 1 < 262144) ? whhf[e + 1] : whhb[e + 1 - 262144];
    int p = __builtin_amdgcn_cvt_pk_fp8_f32(a, b, 0, false);
    *(unsigned short*)(dst + e) = (unsigned short)(p & 0xffff);
}

// ---------------- embedding gather -> e_t[t*64+b][256] bf16 ----------------
__global__ void k_gather(const int* __restrict__ x, const float* __restrict__ emb,
                         unsigned short* __restrict__ et) {
    int id = blockIdx.x * 256 + threadIdx.x;   // 1,048,576 total
    int m = id >> 5, fi = (id & 31) << 3;
    int b = m & 63, t = m >> 6;
    int v = x[b * 512 + t];
    const float4* s = (const float4*)(emb + ((size_t)v << 8) + fi);
    float4 a = s[0], q = s[1];
    uint4 o;
    o.x = (unsigned)f2bf(a.x) | ((unsigned)f2bf(a.y) << 16);
    o.y = (unsigned)f2bf(a.z) | ((unsigned)f2bf(a.w) << 16);
    o.z = (unsigned)f2bf(q.x) | ((unsigned)f2bf(q.y) << 16);
    o.w = (unsigned)f2bf(q.z) | ((unsigned)f2bf(q.w) << 16);
    *(uint4*)(et + ((size_t)m << 8) + fi) = o;
}

// ---------------- gx = e @ w_ih.T + b, both dirs (N=2048), output bf16 [d][t][b][1024] ----------------
__global__ __launch_bounds__(256, 2) void k_gx(const unsigned short* __restrict__ et,
                                               const unsigned short* __restrict__ wcat,
                                               const float* __restrict__ bfv, const float* __restrict__ bbv,
                                               unsigned short* __restrict__ gx) {
    __shared__ unsigned short As[4096];
    __shared__ unsigned short Bs[4096];
    const int tid = threadIdx.x;
    const int w = tid >> 6, l = tid & 63, quad = l >> 4, col = l & 15;
    const size_t m0 = (size_t)blockIdx.x * 128, n0 = (size_t)blockIdx.y * 128;
    floatx4 C[4][4];
    #pragma unroll
    for (int i = 0; i < 4; ++i)
        #pragma unroll
        for (int j = 0; j < 4; ++j) C[i][j] = (floatx4){0.f, 0.f, 0.f, 0.f};
    const int srow = tid >> 2, scol = (tid & 3) * 16;
    for (int it = 0; it < 8; ++it) {
        const char* ga = (const char*)et + (m0 + srow) * 512 + it * 64 + scol;
        const char* gb = (const char*)wcat + (n0 + srow) * 512 + it * 64 + scol;
        glds16(ga,             (char*)As + w * 1024);
        glds16(ga + 64 * 512,  (char*)As + 4096 + w * 1024);
        glds16(gb,             (char*)Bs + w * 1024);
        glds16(gb + 64 * 512,  (char*)Bs + 4096 + w * 1024);
        __syncthreads();
        short8 Af[4], Bf[4];
        #pragma unroll
        for (int i = 0; i < 4; ++i) {
            Af[i] = *(const short8*)(As + (((w & 1) * 64 + i * 16 + col) * 32 + quad * 8));
            Bf[i] = *(const short8*)(Bs + (((w >> 1) * 64 + i * 16 + col) * 32 + quad * 8));
        }
        #pragma unroll
        for (int i = 0; i < 4; ++i)
            #pragma unroll
            for (int j = 0; j < 4; ++j)
                C[i][j] = __builtin_amdgcn_mfma_f32_16x16x32_bf16(Af[i], Bf[j], C[i][j], 0, 0, 0);
        __syncthreads();
    }
    const int mw = (w & 1) * 64, nw = (w >> 1) * 64;
    #pragma unroll
    for (int j = 0; j < 4; ++j) {
        int n = (int)n0 + nw + j * 16 + col;
        float bias = (n < 1024) ? bfv[n] : bbv[n - 1024];
        size_t dbase = (size_t)(n >> 10) * 33554432 + (size_t)(n & 1023);
        #pragma unroll
        for (int i = 0; i < 4; ++i)
            #pragma unroll
            for (int r = 0; r < 4; ++r) {
                size_t m = m0 + mw + i * 16 + quad * 4 + r;
                gx[dbase + m * 1024] = f2bf(C[i][j][r] + bias);
            }
    }
}

// ---------------- LSTM recurrence: 16 wgs = 2 dirs x 8 batch-groups of 8 ----------------
// MFMA phase: z = W(fp8, reg-resident) @ h(fp8, LDS); z -> zB (LDS, f32).
// Gate phase: thread (wave=batch, lane=unit-quad) reads zB + coalesced gx, computes
// gates (4 quads/thread), writes h to hld (fp8) + hcat (bf16 global). 2 barriers/step.
__global__ __launch_bounds__(512, 2) void k_lstm(const unsigned char* __restrict__ w8_all,
                                                 const unsigned short* __restrict__ gx_all,
                                                 unsigned short* __restrict__ hcat) {
    const int d = blockIdx.x >> 3, bg = blockIdx.x & 7;
    const int tid = threadIdx.x, w = tid >> 6, l = tid & 63, quad = l >> 4, col = l & 15;
    const unsigned char* W = w8_all + (size_t)d * 262144;
    const unsigned short* G = gx_all + (size_t)d * 33554432;
    __shared__ __align__(16) float zB[8][4][260];          // 33,280 B  z[batch][gate][unit]
    __shared__ __align__(16) unsigned char hld[16][280];   //  4,480 B  h fp8 [batch][unit]

    // A-fragments: lane holds W[16*mt + col][kt*32 + quad*8 + j], j=0..7 (8 bytes)
    long Wr[8][8];   // [kt][a], mt(a) = 2w + (a&1) + 16*(a>>1)
    #pragma unroll
    for (int kt = 0; kt < 8; ++kt)
        #pragma unroll
        for (int a = 0; a < 8; ++a) {
            int mt = 2 * w + (a & 1) + 16 * (a >> 1);
            Wr[kt][a] = *(const long*)(W + (size_t)(16 * mt + col) * 256 + kt * 32 + quad * 8);
        }
    for (int i = tid; i < 1120; i += 512) ((unsigned int*)hld)[i] = 0;

    float cst[4] = {0.f, 0.f, 0.f, 0.f};
    const int bglob = bg * 8 + w;   // this wave's batch in the gate phase
    __syncthreads();

    #pragma clang loop unroll(disable)
    for (int step = 0; step < 512; ++step) {
        const int t = d ? (511 - step) : step;
        // coalesced gx prefetch for the gate phase (4 gates x 4 units)
        uint2 gq[4];
        #pragma unroll
        for (int g = 0; g < 4; ++g)
            gq[g] = *(const uint2*)(G + ((size_t)(t * 64 + bglob) * 1024 + g * 256 + 4 * l));
        // B-fragments: lane holds h_fp8[batch=col][k = kt*32 + quad*8 + j]
        long Bf[8];
        #pragma unroll
        for (int kt = 0; kt < 8; ++kt)
            Bf[kt] = *(const long*)(&hld[col][kt * 32 + quad * 8]);
        floatx4 C[8];
        #pragma unroll
        for (int a = 0; a < 8; ++a) C[a] = (floatx4){0.f, 0.f, 0.f, 0.f};
        #pragma unroll
        for (int kt = 0; kt < 8; ++kt)
            #pragma unroll
            for (int a = 0; a < 8; ++a)
                C[a] = __builtin_amdgcn_mfma_f32_16x16x32_fp8_fp8(Wr[kt][a], Bf[kt], C[a], 0, 0, 0);
        // scatter z to LDS (only batches 0..7 are real)
        if (col < 8) {
            #pragma unroll
            for (int a = 0; a < 8; ++a) {
                int gate = a >> 1;
                int u0 = 32 * w + 16 * (a & 1) + 4 * quad;
                #pragma unroll
                for (int r = 0; r < 4; ++r) zB[col][gate][u0 + r] = C[a][r];
            }
        }
        __syncthreads();
        // ---- gate phase: batch = bglob, units 4l..4l+3 ----
        float zi[4], zf[4], zg[4], zo[4];
        *(float4*)zi = *(const float4*)&zB[w][0][4 * l];
        *(float4*)zf = *(const float4*)&zB[w][1][4 * l];
        *(float4*)zg = *(const float4*)&zB[w][2][4 * l];
        *(float4*)zo = *(const float4*)&zB[w][3][4 * l];
        float hf[4];
        #pragma unroll
        for (int i = 0; i < 4; ++i) {
            float gi = bf2f((unsigned short)(((i & 2) ? gq[0].y : gq[0].x) >> ((i & 1) * 16)));
            float gf = bf2f((unsigned short)(((i & 2) ? gq[1].y : gq[1].x) >> ((i & 1) * 16)));
            float gg = bf2f((unsigned short)(((i & 2) ? gq[2].y : gq[2].x) >> ((i & 1) * 16)));
            float go = bf2f((unsigned short)(((i & 2) ? gq[3].y : gq[3].x) >> ((i & 1) * 16)));
            float vi = zi[i] + gi, vf = zf[i] + gf, vg = zg[i] + gg, vo = zo[i] + go;
            float cc = sigm(vf) * cst[i] + sigm(vi) * tanh_(vg);
            cst[i] = cc;
            hf[i] = sigm(vo) * tanh_(cc);
        }
        uint2 hb;
        hb.x = (unsigned)f2bf(hf[0]) | ((unsigned)f2bf(hf[1]) << 16);
        hb.y = (unsigned)f2bf(hf[2]) | ((unsigned)f2bf(hf[3]) << 16);
        *(uint2*)(hcat + ((size_t)(t * 64 + bglob) * 512 + d * 256 + 4 * l)) = hb;
        int lo = __builtin_amdgcn_cvt_pk_fp8_f32(hf[0], hf[1], 0, false);
        int fu = __builtin_amdgcn_cvt_pk_fp8_f32(hf[2], hf[3], lo, true);
        *(unsigned int*)(&hld[w][4 * l]) = (unsigned int)fu;
        __syncthreads();
    }
}

// ---------------- scores = hcat @ w_fc.T + b_fc, fp32 [t][b][32] ----------------
__global__ __launch_bounds__(256, 4) void k_scores(const unsigned short* __restrict__ hcat,
                                                   const unsigned short* __restrict__ wfc,
                                                   const float* __restrict__ bfc,
                                                   float* __restrict__ sc) {
    const int tid = threadIdx.x, w = tid >> 6, l = tid & 63, quad = l >> 4, col = l & 15;
    const int m0 = blockIdx.x * 64 + w * 16;
    floatx4 C0 = (floatx4){0.f, 0.f, 0.f, 0.f}, C1 = C0;
    #pragma unroll
    for (int kt = 0; kt < 16; ++kt) {
        short8 A  = *(const short8*)(hcat + (size_t)(m0 + col) * 512 + kt * 32 + quad * 8);
        short8 B0 = *(const short8*)(wfc + (size_t)col * 512 + kt * 32 + quad * 8);
        short8 B1 = *(const short8*)(wfc + (size_t)(16 + col) * 512 + kt * 32 + quad * 8);
        C0 = __builtin_amdgcn_mfma_f32_16x16x32_bf16(A, B0, C0, 0, 0, 0);
        C1 = __builtin_amdgcn_mfma_f32_16x16x32_bf16(A, B1, C1, 0, 0, 0);
    }
    float b0 = bfc[col], b1 = bfc[16 + col];
    #pragma unroll
    for (int r = 0; r < 4; ++r) {
        int m = m0 + quad * 4 + r;
        sc[(size_t)m * 32 + col] = C0[r] + b0;
        sc[(size_t)m * 32 + 16 + col] = C1[r] + b1;
    }
}

// ---------------- CRF: true path score + forward algorithm, loss += total - true ----------------
__global__ __launch_bounds__(1024, 1) void k_crf(const float* __restrict__ sc, const int* __restrict__ tags,
                                                 const int* __restrict__ mask, const float* __restrict__ tr,
                                                 float* __restrict__ out) {
    __shared__ float Tm[32][33];
    __shared__ float alpha[32];
    __shared__ float trueb;
    const int b = blockIdx.x, tid = threadIdx.x;
    { int i = tid >> 5, j = tid & 31; Tm[i][j] = tr[tid]; }
    __syncthreads();
    if (tid < 64) {
        float acc = 0.f; int cnt = 0;
        for (int t = tid; t < 512; t += 64) cnt += mask[b * 512 + t];
        for (int t = tid + 1; t < 512; t += 64) {
            if (mask[b * 512 + t]) {
                int tg = tags[b * 512 + t], tp = tags[b * 512 + t - 1];
                acc += Tm[tp][tg] + sc[((size_t)t * 64 + b) * 32 + tg];
            }
        }
        #pragma unroll
        for (int m = 1; m < 64; m <<= 1) { acc += __shfl_xor(acc, m); cnt += __shfl_xor(cnt, m); }
        if (tid == 0) {
            int tg0 = tags[b * 512];
            float first = Tm[30][tg0] + sc[(size_t)b * 32 + tg0];
            int lt = tags[b * 512 + cnt - 1];
            trueb = first + acc + Tm[lt][31];
        }
    }
    if (tid < 32) alpha[tid] = Tm[30][tid] + sc[(size_t)b * 32 + tid];
    __syncthreads();
    const int j = tid >> 5, i = tid & 31;
    #pragma clang loop unroll(disable)
    for (int t = 1; t < 512; ++t) {
        float v = alpha[i] + Tm[i][j];
        float mx = v;
        #pragma unroll
        for (int m = 1; m < 32; m <<= 1) mx = fmaxf(mx, __shfl_xor(mx, m));
        float e = __expf(v - mx);
        #pragma unroll
        for (int m = 1; m < 32; m <<= 1) e += __shfl_xor(e, m);
        float nv = mx + __logf(e) + sc[((size_t)t * 64 + b) * 32 + j];
        int mk = mask[b * 512 + t];
        __syncthreads();
        if (mk && i == 0) alpha[j] = nv;
        __syncthreads();
    }
    if (tid < 32) {
        float v = alpha[tid] + Tm[tid][31];
        float mx = v;
        #pragma unroll
        for (int m = 1; m < 32; m <<= 1) mx = fmaxf(mx, __shfl_xor(mx, m));
        float e = __expf(v - mx);
        #pragma unroll
        for (int m = 1; m < 32; m <<= 1) e += __shfl_xor(e, m);
        if (tid == 0) atomicAdd(out, mx + __logf(e) - trueb);
    }
}

extern "C" void kernel_launch(void* const* d_in, const int* in_sizes, int n_in,
                              void* d_out, int out_size, void* d_ws, size_t ws_size,
                              hipStream_t stream) {
    const int* x      = (const int*)d_in[0];
    const int* tags   = (const int*)d_in[1];
    const int* mask   = (const int*)d_in[2];
    const float* emb  = (const float*)d_in[3];
    const float* wihf = (const float*)d_in[4];
    const float* whhf = (const float*)d_in[5];
    const float* bf_  = (const float*)d_in[6];
    const float* wihb = (const float*)d_in[7];
    const float* whhb = (const float*)d_in[8];
    const float* bb_  = (const float*)d_in[9];
    const float* wfc  = (const float*)d_in[10];
    const float* bfc  = (const float*)d_in[11];
    const float* tr   = (const float*)d_in[12];

    char* ws = (char*)d_ws;
    unsigned short* et   = (unsigned short*)(ws);                 //  16,777,216 B
    unsigned short* wbf  = (unsigned short*)(ws + 16777216);      //   1,064,960 B (wih f|b cat, then wfc @ elem 524288)
    unsigned char*  w8   = (unsigned char*)(ws + 17842176);      //     524,288 B (whh f|b fp8)
    unsigned short* gx   = (unsigned short*)(ws + 18366464);      // 134,217,728 B
    unsigned short* hcat = (unsigned short*)(ws + 152584192);     //  33,554,432 B
    float* sc            = (float*)(ws + 186138624);              //   4,194,304 B

    hipMemsetAsync(d_out, 0, sizeof(float), stream);
    k_cast_weights<<<2080, 256, 0, stream>>>(wihf, wihb, wfc, wbf);
    k_cast_fp8<<<1024, 256, 0, stream>>>(whhf, whhb, w8);
    k_gather<<<4096, 256, 0, stream>>>(x, emb, et);
    dim3 g2(256, 16);
    k_gx<<<g2, 256, 0, stream>>>(et, wbf, bf_, bb_, gx);
    k_lstm<<<16, 512, 0, stream>>>(w8, gx, hcat);
    k_scores<<<512, 256, 0, stream>>>(hcat, wbf + 524288, bfc, sc);
    k_crf<<<64, 1024, 0, stream>>>(sc, tags, mask, tr, (float*)d_out);
}

// Round 4
// 1522.555 us; speedup vs baseline: 3.6162x; 1.2932x over previous
//
#include <hip/hip_runtime.h>

typedef __attribute__((ext_vector_type(8))) short short8;
typedef __attribute__((ext_vector_type(4))) float floatx4;

__device__ __forceinline__ float bf2f(unsigned short u) {
    union { unsigned int i; float f; } c; c.i = ((unsigned int)u) << 16; return c.f;
}
__device__ __forceinline__ unsigned short f2bf(float f) {
    union { float f; unsigned int i; } c; c.f = f;
    unsigned int u = c.i;
    return (unsigned short)((u + 0x7FFFu + ((u >> 16) & 1u)) >> 16);
}
// fast sigmoid/tanh: native v_exp + v_rcp (no IEEE div sequence)
__device__ __forceinline__ float sigm(float x) {
    return __builtin_amdgcn_rcpf(1.f + __expf(-x));
}
__device__ __forceinline__ float tanh_(float x) {
    return 1.f - 2.f * __builtin_amdgcn_rcpf(1.f + __expf(2.f * x));
}

__device__ __forceinline__ void glds16(const void* g, void* l) {
    __builtin_amdgcn_global_load_lds((const __attribute__((address_space(1))) unsigned int*)g,
                                     (__attribute__((address_space(3))) unsigned int*)l, 16, 0, 0);
}

// ---------------- cast weights to bf16 (w_ih_f | w_ih_b | w_fc) ----------------
__global__ void k_cast_weights(const float* __restrict__ wihf, const float* __restrict__ wihb,
                               const float* __restrict__ wfc, unsigned short* __restrict__ dst) {
    int i = blockIdx.x * 256 + threadIdx.x;
    if (i >= 532480) return;
    float v;
    if (i < 262144) v = wihf[i];
    else if (i < 524288) v = wihb[i - 262144];
    else v = wfc[i - 524288];
    dst[i] = f2bf(v);
}

// ---------------- cast w_hh (f|b) to fp8 e4m3 ----------------
__global__ void k_cast_fp8(const float* __restrict__ whhf, const float* __restrict__ whhb,
                           unsigned char* __restrict__ dst) {
    int i = blockIdx.x * 256 + threadIdx.x;   // 262144 threads, 2 elems each
    if (i >= 262144) return;
    int e = i * 2;
    float a = (e < 262144) ? whhf[e] : whhb[e - 262144];
    float b = (e + 1 < 262144) ? whhf[e + 1] : whhb[e + 1 - 262144];
    int p = __builtin_amdgcn_cvt_pk_fp8_f32(a, b, 0, false);
    *(unsigned short*)(dst + e) = (unsigned short)(p & 0xffff);
}

// ---------------- embedding gather -> e_t[t*64+b][256] bf16 ----------------
__global__ void k_gather(const int* __restrict__ x, const float* __restrict__ emb,
                         unsigned short* __restrict__ et) {
    int id = blockIdx.x * 256 + threadIdx.x;   // 1,048,576 total
    int m = id >> 5, fi = (id & 31) << 3;
    int b = m & 63, t = m >> 6;
    int v = x[b * 512 + t];
    const float4* s = (const float4*)(emb + ((size_t)v << 8) + fi);
    float4 a = s[0], q = s[1];
    uint4 o;
    o.x = (unsigned)f2bf(a.x) | ((unsigned)f2bf(a.y) << 16);
    o.y = (unsigned)f2bf(a.z) | ((unsigned)f2bf(a.w) << 16);
    o.z = (unsigned)f2bf(q.x) | ((unsigned)f2bf(q.y) << 16);
    o.w = (unsigned)f2bf(q.z) | ((unsigned)f2bf(q.w) << 16);
    *(uint4*)(et + ((size_t)m << 8) + fi) = o;
}

// ---------------- gx = e @ w_ih.T + b, both dirs (N=2048), output bf16 [d][t][b][1024] ----------------
__global__ __launch_bounds__(256, 2) void k_gx(const unsigned short* __restrict__ et,
                                               const unsigned short* __restrict__ wcat,
                                               const float* __restrict__ bfv, const float* __restrict__ bbv,
                                               unsigned short* __restrict__ gx) {
    __shared__ unsigned short As[4096];
    __shared__ unsigned short Bs[4096];
    const int tid = threadIdx.x;
    const int w = tid >> 6, l = tid & 63, quad = l >> 4, col = l & 15;
    const size_t m0 = (size_t)blockIdx.x * 128, n0 = (size_t)blockIdx.y * 128;
    floatx4 C[4][4];
    #pragma unroll
    for (int i = 0; i < 4; ++i)
        #pragma unroll
        for (int j = 0; j < 4; ++j) C[i][j] = (floatx4){0.f, 0.f, 0.f, 0.f};
    const int srow = tid >> 2, scol = (tid & 3) * 16;
    for (int it = 0; it < 8; ++it) {
        const char* ga = (const char*)et + (m0 + srow) * 512 + it * 64 + scol;
        const char* gb = (const char*)wcat + (n0 + srow) * 512 + it * 64 + scol;
        glds16(ga,             (char*)As + w * 1024);
        glds16(ga + 64 * 512,  (char*)As + 4096 + w * 1024);
        glds16(gb,             (char*)Bs + w * 1024);
        glds16(gb + 64 * 512,  (char*)Bs + 4096 + w * 1024);
        __syncthreads();
        short8 Af[4], Bf[4];
        #pragma unroll
        for (int i = 0; i < 4; ++i) {
            Af[i] = *(const short8*)(As + (((w & 1) * 64 + i * 16 + col) * 32 + quad * 8));
            Bf[i] = *(const short8*)(Bs + (((w >> 1) * 64 + i * 16 + col) * 32 + quad * 8));
        }
        #pragma unroll
        for (int i = 0; i < 4; ++i)
            #pragma unroll
            for (int j = 0; j < 4; ++j)
                C[i][j] = __builtin_amdgcn_mfma_f32_16x16x32_bf16(Af[i], Bf[j], C[i][j], 0, 0, 0);
        __syncthreads();
    }
    const int mw = (w & 1) * 64, nw = (w >> 1) * 64;
    #pragma unroll
    for (int j = 0; j < 4; ++j) {
        int n = (int)n0 + nw + j * 16 + col;
        float bias = (n < 1024) ? bfv[n] : bbv[n - 1024];
        size_t dbase = (size_t)(n >> 10) * 33554432 + (size_t)(n & 1023);
        #pragma unroll
        for (int i = 0; i < 4; ++i)
            #pragma unroll
            for (int r = 0; r < 4; ++r) {
                size_t m = m0 + mw + i * 16 + quad * 4 + r;
                gx[dbase + m * 1024] = f2bf(C[i][j][r] + bias);
            }
    }
}

// ---------------- LSTM recurrence: 16 wgs = 2 dirs x 8 batch-groups of 8; 1024 thr (16 waves) ----
// MFMA phase: wave w owns gate (w>>2), unit-tiles 4*(w&3)..+3; W fp8 reg-resident (64 VGPR).
// z -> zB (LDS f32, b128 stores). Gate phase: thread = (batch = tid>>7, units 2j,2j+1).
// h: fp8 -> hld (LDS) for next step's B-frags; bf16 -> hcat (global). 2 barriers/step.
__global__ __launch_bounds__(1024, 4) void k_lstm(const unsigned char* __restrict__ w8_all,
                                                  const unsigned short* __restrict__ gx_all,
                                                  unsigned short* __restrict__ hcat) {
    const int d = blockIdx.x >> 3, bg = blockIdx.x & 7;
    const int tid = threadIdx.x, w = tid >> 6, l = tid & 63, quad = l >> 4, col = l & 15;
    const unsigned char* W = w8_all + (size_t)d * 262144;
    const unsigned short* G = gx_all + (size_t)d * 33554432;
    __shared__ __align__(16) float zB[8][4][260];          // 33,280 B  z[batch][gate][unit]
    __shared__ __align__(16) unsigned char hld[8][288];    //   2,304 B  h fp8 [batch][unit]

    // A-fragments: wave w, tile a: W rows 16*(4w+a)..+15; lane holds row 16*(4w+a)+col,
    // k = kt*32 + quad*8 + j (8 bytes)
    long Wr[8][4];
    #pragma unroll
    for (int kt = 0; kt < 8; ++kt)
        #pragma unroll
        for (int a = 0; a < 4; ++a)
            Wr[kt][a] = *(const long*)(W + (size_t)(16 * (4 * w + a) + col) * 256 + kt * 32 + quad * 8);
    for (int i = tid; i < 576; i += 1024) ((unsigned int*)hld)[i] = 0;

    const int gate_w = w >> 2, ut0 = (w & 3) * 4;          // scatter coords
    const int batch = tid >> 7, j = tid & 127;             // gate-phase coords
    const int bglob = bg * 8 + batch;
    float cst[2] = {0.f, 0.f};
    unsigned int gc[4], gn[4];
    {
        int t0 = d ? 511 : 0;
        #pragma unroll
        for (int g = 0; g < 4; ++g)
            gc[g] = *(const unsigned int*)(G + ((size_t)(t0 * 64 + bglob) * 1024 + g * 256 + 2 * j));
    }
    __syncthreads();

    auto body = [&](unsigned int (&gcur)[4], unsigned int (&gnext)[4], int tcur, int tnext) {
        // prefetch next step's gx (full step of latency cover)
        #pragma unroll
        for (int g = 0; g < 4; ++g)
            gnext[g] = *(const unsigned int*)(G + ((size_t)(tnext * 64 + bglob) * 1024 + g * 256 + 2 * j));
        // ---- MFMA phase ----
        floatx4 C[4];
        #pragma unroll
        for (int a = 0; a < 4; ++a) C[a] = (floatx4){0.f, 0.f, 0.f, 0.f};
        #pragma unroll
        for (int kt = 0; kt < 8; ++kt) {
            long Bf = *(const long*)(&hld[col & 7][kt * 32 + quad * 8]);
            #pragma unroll
            for (int a = 0; a < 4; ++a)
                C[a] = __builtin_amdgcn_mfma_f32_16x16x32_fp8_fp8(Wr[kt][a], Bf, C[a], 0, 0, 0);
        }
        if (col < 8) {
            #pragma unroll
            for (int a = 0; a < 4; ++a)
                *(float4*)(&zB[col][gate_w][(ut0 + a) * 16 + 4 * quad]) = *(float4*)&C[a];
        }
        __syncthreads();
        // ---- gate phase: (batch, units 2j, 2j+1) ----
        float2 zi = *(const float2*)&zB[batch][0][2 * j];
        float2 zf = *(const float2*)&zB[batch][1][2 * j];
        float2 zg = *(const float2*)&zB[batch][2][2 * j];
        float2 zo = *(const float2*)&zB[batch][3][2 * j];
        float hf[2];
        #pragma unroll
        for (int u = 0; u < 2; ++u) {
            float gi = bf2f((unsigned short)(gcur[0] >> (u * 16)));
            float gf = bf2f((unsigned short)(gcur[1] >> (u * 16)));
            float gg = bf2f((unsigned short)(gcur[2] >> (u * 16)));
            float go = bf2f((unsigned short)(gcur[3] >> (u * 16)));
            float vi = (u ? zi.y : zi.x) + gi;
            float vf = (u ? zf.y : zf.x) + gf;
            float vg = (u ? zg.y : zg.x) + gg;
            float vo = (u ? zo.y : zo.x) + go;
            float cc = sigm(vf) * cst[u] + sigm(vi) * tanh_(vg);
            cst[u] = cc;
            hf[u] = sigm(vo) * tanh_(cc);
        }
        unsigned int hb = (unsigned)f2bf(hf[0]) | ((unsigned)f2bf(hf[1]) << 16);
        *(unsigned int*)(hcat + ((size_t)(tcur * 64 + bglob) * 512 + d * 256 + 2 * j)) = hb;
        int pk = __builtin_amdgcn_cvt_pk_fp8_f32(hf[0], hf[1], 0, false);
        *(unsigned short*)(&hld[batch][2 * j]) = (unsigned short)(pk & 0xffff);
        __syncthreads();
    };

    #pragma clang loop unroll(disable)
    for (int step = 0; step < 512; step += 2) {
        int tA = d ? 511 - step : step;
        int tB = d ? 510 - step : step + 1;
        int sC = (step + 2) & 511;
        int tC = d ? 511 - sC : sC;
        body(gc, gn, tA, tB);
        body(gn, gc, tB, tC);
    }
}

// ---------------- scores = hcat @ w_fc.T + b_fc, fp32 [t][b][32] ----------------
__global__ __launch_bounds__(256, 4) void k_scores(const unsigned short* __restrict__ hcat,
                                                   const unsigned short* __restrict__ wfc,
                                                   const float* __restrict__ bfc,
                                                   float* __restrict__ sc) {
    const int tid = threadIdx.x, w = tid >> 6, l = tid & 63, quad = l >> 4, col = l & 15;
    const int m0 = blockIdx.x * 64 + w * 16;
    floatx4 C0 = (floatx4){0.f, 0.f, 0.f, 0.f}, C1 = C0;
    #pragma unroll
    for (int kt = 0; kt < 16; ++kt) {
        short8 A  = *(const short8*)(hcat + (size_t)(m0 + col) * 512 + kt * 32 + quad * 8);
        short8 B0 = *(const short8*)(wfc + (size_t)col * 512 + kt * 32 + quad * 8);
        short8 B1 = *(const short8*)(wfc + (size_t)(16 + col) * 512 + kt * 32 + quad * 8);
        C0 = __builtin_amdgcn_mfma_f32_16x16x32_bf16(A, B0, C0, 0, 0, 0);
        C1 = __builtin_amdgcn_mfma_f32_16x16x32_bf16(A, B1, C1, 0, 0, 0);
    }
    float b0 = bfc[col], b1 = bfc[16 + col];
    #pragma unroll
    for (int r = 0; r < 4; ++r) {
        int m = m0 + quad * 4 + r;
        sc[(size_t)m * 32 + col] = C0[r] + b0;
        sc[(size_t)m * 32 + 16 + col] = C1[r] + b1;
    }
}

// ---------------- CRF: true path score + forward algorithm, loss += total - true ----------------
__global__ __launch_bounds__(1024, 1) void k_crf(const float* __restrict__ sc, const int* __restrict__ tags,
                                                 const int* __restrict__ mask, const float* __restrict__ tr,
                                                 float* __restrict__ out) {
    __shared__ float Tm[32][33];
    __shared__ float alpha[32];
    __shared__ float trueb;
    const int b = blockIdx.x, tid = threadIdx.x;
    { int i = tid >> 5, j = tid & 31; Tm[i][j] = tr[tid]; }
    __syncthreads();
    if (tid < 64) {
        float acc = 0.f; int cnt = 0;
        for (int t = tid; t < 512; t += 64) cnt += mask[b * 512 + t];
        for (int t = tid + 1; t < 512; t += 64) {
            if (mask[b * 512 + t]) {
                int tg = tags[b * 512 + t], tp = tags[b * 512 + t - 1];
                acc += Tm[tp][tg] + sc[((size_t)t * 64 + b) * 32 + tg];
            }
        }
        #pragma unroll
        for (int m = 1; m < 64; m <<= 1) { acc += __shfl_xor(acc, m); cnt += __shfl_xor(cnt, m); }
        if (tid == 0) {
            int tg0 = tags[b * 512];
            float first = Tm[30][tg0] + sc[(size_t)b * 32 + tg0];
            int lt = tags[b * 512 + cnt - 1];
            trueb = first + acc + Tm[lt][31];
        }
    }
    if (tid < 32) alpha[tid] = Tm[30][tid] + sc[(size_t)b * 32 + tid];
    __syncthreads();
    const int j = tid >> 5, i = tid & 31;
    #pragma clang loop unroll(disable)
    for (int t = 1; t < 512; ++t) {
        float v = alpha[i] + Tm[i][j];
        float mx = v;
        #pragma unroll
        for (int m = 1; m < 32; m <<= 1) mx = fmaxf(mx, __shfl_xor(mx, m));
        float e = __expf(v - mx);
        #pragma unroll
        for (int m = 1; m < 32; m <<= 1) e += __shfl_xor(e, m);
        float nv = mx + __logf(e) + sc[((size_t)t * 64 + b) * 32 + j];
        int mk = mask[b * 512 + t];
        __syncthreads();
        if (mk && i == 0) alpha[j] = nv;
        __syncthreads();
    }
    if (tid < 32) {
        float v = alpha[tid] + Tm[tid][31];
        float mx = v;
        #pragma unroll
        for (int m = 1; m < 32; m <<= 1) mx = fmaxf(mx, __shfl_xor(mx, m));
        float e = __expf(v - mx);
        #pragma unroll
        for (int m = 1; m < 32; m <<= 1) e += __shfl_xor(e, m);
        if (tid == 0) atomicAdd(out, mx + __logf(e) - trueb);
    }
}

extern "C" void kernel_launch(void* const* d_in, const int* in_sizes, int n_in,
                              void* d_out, int out_size, void* d_ws, size_t ws_size,
                              hipStream_t stream) {
    const int* x      = (const int*)d_in[0];
    const int* tags   = (const int*)d_in[1];
    const int* mask   = (const int*)d_in[2];
    const float* emb  = (const float*)d_in[3];
    const float* wihf = (const float*)d_in[4];
    const float* whhf = (const float*)d_in[5];
    const float* bf_  = (const float*)d_in[6];
    const float* wihb = (const float*)d_in[7];
    const float* whhb = (const float*)d_in[8];
    const float* bb_  = (const float*)d_in[9];
    const float* wfc  = (const float*)d_in[10];
    const float* bfc  = (const float*)d_in[11];
    const float* tr   = (const float*)d_in[12];

    char* ws = (char*)d_ws;
    unsigned short* et   = (unsigned short*)(ws);                 //  16,777,216 B
    unsigned short* wbf  = (unsigned short*)(ws + 16777216);      //   1,064,960 B (wih f|b cat, then wfc @ elem 524288)
    unsigned char*  w8   = (unsigned char*)(ws + 17842176);      //     524,288 B (whh f|b fp8)
    unsigned short* gx   = (unsigned short*)(ws + 18366464);      // 134,217,728 B
    unsigned short* hcat = (unsigned short*)(ws + 152584192);     //  33,554,432 B
    float* sc            = (float*)(ws + 186138624);              //   4,194,304 B

    hipMemsetAsync(d_out, 0, sizeof(float), stream);
    k_cast_weights<<<2080, 256, 0, stream>>>(wihf, wihb, wfc, wbf);
    k_cast_fp8<<<1024, 256, 0, stream>>>(whhf, whhb, w8);
    k_gather<<<4096, 256, 0, stream>>>(x, emb, et);
    dim3 g2(256, 16);
    k_gx<<<g2, 256, 0, stream>>>(et, wbf, bf_, bb_, gx);
    k_lstm<<<16, 1024, 0, stream>>>(w8, gx, hcat);
    k_scores<<<512, 256, 0, stream>>>(hcat, wbf + 524288, bfc, sc);
    k_crf<<<64, 1024, 0, stream>>>(sc, tags, mask, tr, (float*)d_out);
}

// Round 5
// 1484.776 us; speedup vs baseline: 3.7082x; 1.0254x over previous
//
#include <hip/hip_runtime.h>

typedef __attribute__((ext_vector_type(8))) short short8;
typedef __attribute__((ext_vector_type(4))) float floatx4;

__device__ __forceinline__ float bf2f(unsigned short u) {
    union { unsigned int i; float f; } c; c.i = ((unsigned int)u) << 16; return c.f;
}
__device__ __forceinline__ unsigned short f2bf(float f) {
    union { float f; unsigned int i; } c; c.f = f;
    unsigned int u = c.i;
    return (unsigned short)((u + 0x7FFFu + ((u >> 16) & 1u)) >> 16);
}
// truncating bf16 (cheap, used for h output; |h|<1 so error ≤ 0.4% with huge loss slack)
__device__ __forceinline__ unsigned short f2bf_rz(float f) {
    union { float f; unsigned int i; } c; c.f = f;
    return (unsigned short)(c.i >> 16);
}
// fast sigmoid/tanh: native v_exp + v_rcp (no IEEE div sequence)
__device__ __forceinline__ float sigm(float x) {
    return __builtin_amdgcn_rcpf(1.f + __expf(-x));
}
__device__ __forceinline__ float tanh_(float x) {
    return 1.f - 2.f * __builtin_amdgcn_rcpf(1.f + __expf(2.f * x));
}

__device__ __forceinline__ void glds16(const void* g, void* l) {
    __builtin_amdgcn_global_load_lds((const __attribute__((address_space(1))) unsigned int*)g,
                                     (__attribute__((address_space(3))) unsigned int*)l, 16, 0, 0);
}

// ---------------- cast weights to bf16 (w_ih_f | w_ih_b | w_fc) ----------------
__global__ void k_cast_weights(const float* __restrict__ wihf, const float* __restrict__ wihb,
                               const float* __restrict__ wfc, unsigned short* __restrict__ dst) {
    int i = blockIdx.x * 256 + threadIdx.x;
    if (i >= 532480) return;
    float v;
    if (i < 262144) v = wihf[i];
    else if (i < 524288) v = wihb[i - 262144];
    else v = wfc[i - 524288];
    dst[i] = f2bf(v);
}

// ---------------- cast w_hh (f|b) to fp8 e4m3 ----------------
__global__ void k_cast_fp8(const float* __restrict__ whhf, const float* __restrict__ whhb,
                           unsigned char* __restrict__ dst) {
    int i = blockIdx.x * 256 + threadIdx.x;   // 262144 threads, 2 elems each
    if (i >= 262144) return;
    int e = i * 2;
    float a = (e < 262144) ? whhf[e] : whhb[e - 262144];
    float b = (e + 1 < 262144) ? whhf[e + 1] : whhb[e + 1 - 262144];
    int p = __builtin_amdgcn_cvt_pk_fp8_f32(a, b, 0, false);
    *(unsigned short*)(dst + e) = (unsigned short)(p & 0xffff);
}

// ---------------- embedding gather -> e_t[t*64+b][256] bf16 ----------------
__global__ void k_gather(const int* __restrict__ x, const float* __restrict__ emb,
                         unsigned short* __restrict__ et) {
    int id = blockIdx.x * 256 + threadIdx.x;   // 1,048,576 total
    int m = id >> 5, fi = (id & 31) << 3;
    int b = m & 63, t = m >> 6;
    int v = x[b * 512 + t];
    const float4* s = (const float4*)(emb + ((size_t)v << 8) + fi);
    float4 a = s[0], q = s[1];
    uint4 o;
    o.x = (unsigned)f2bf(a.x) | ((unsigned)f2bf(a.y) << 16);
    o.y = (unsigned)f2bf(a.z) | ((unsigned)f2bf(a.w) << 16);
    o.z = (unsigned)f2bf(q.x) | ((unsigned)f2bf(q.y) << 16);
    o.w = (unsigned)f2bf(q.z) | ((unsigned)f2bf(q.w) << 16);
    *(uint4*)(et + ((size_t)m << 8) + fi) = o;
}

// ---------------- gx = e @ w_ih.T + b, both dirs (N=2048), output bf16 [d][t][b][1024] ----------------
__global__ __launch_bounds__(256, 2) void k_gx(const unsigned short* __restrict__ et,
                                               const unsigned short* __restrict__ wcat,
                                               const float* __restrict__ bfv, const float* __restrict__ bbv,
                                               unsigned short* __restrict__ gx) {
    __shared__ unsigned short As[4096];
    __shared__ unsigned short Bs[4096];
    const int tid = threadIdx.x;
    const int w = tid >> 6, l = tid & 63, quad = l >> 4, col = l & 15;
    const size_t m0 = (size_t)blockIdx.x * 128, n0 = (size_t)blockIdx.y * 128;
    floatx4 C[4][4];
    #pragma unroll
    for (int i = 0; i < 4; ++i)
        #pragma unroll
        for (int j = 0; j < 4; ++j) C[i][j] = (floatx4){0.f, 0.f, 0.f, 0.f};
    const int srow = tid >> 2, scol = (tid & 3) * 16;
    for (int it = 0; it < 8; ++it) {
        const char* ga = (const char*)et + (m0 + srow) * 512 + it * 64 + scol;
        const char* gb = (const char*)wcat + (n0 + srow) * 512 + it * 64 + scol;
        glds16(ga,             (char*)As + w * 1024);
        glds16(ga + 64 * 512,  (char*)As + 4096 + w * 1024);
        glds16(gb,             (char*)Bs + w * 1024);
        glds16(gb + 64 * 512,  (char*)Bs + 4096 + w * 1024);
        __syncthreads();
        short8 Af[4], Bf[4];
        #pragma unroll
        for (int i = 0; i < 4; ++i) {
            Af[i] = *(const short8*)(As + (((w & 1) * 64 + i * 16 + col) * 32 + quad * 8));
            Bf[i] = *(const short8*)(Bs + (((w >> 1) * 64 + i * 16 + col) * 32 + quad * 8));
        }
        #pragma unroll
        for (int i = 0; i < 4; ++i)
            #pragma unroll
            for (int j = 0; j < 4; ++j)
                C[i][j] = __builtin_amdgcn_mfma_f32_16x16x32_bf16(Af[i], Bf[j], C[i][j], 0, 0, 0);
        __syncthreads();
    }
    const int mw = (w & 1) * 64, nw = (w >> 1) * 64;
    #pragma unroll
    for (int j = 0; j < 4; ++j) {
        int n = (int)n0 + nw + j * 16 + col;
        float bias = (n < 1024) ? bfv[n] : bbv[n - 1024];
        size_t dbase = (size_t)(n >> 10) * 33554432 + (size_t)(n & 1023);
        #pragma unroll
        for (int i = 0; i < 4; ++i)
            #pragma unroll
            for (int r = 0; r < 4; ++r) {
                size_t m = m0 + mw + i * 16 + quad * 4 + r;
                gx[dbase + m * 1024] = f2bf(C[i][j][r] + bias);
            }
    }
}

// ---------------- LSTM recurrence: 8 wgs = 2 dirs x 4 batch-groups of 16; 1024 thr ----------------
// Wave w owns units [16w,16w+16): A-tiles = rows 256g+16w (g = i,f,g,o). After MFMA,
// lane (col,quad,r) holds all 4 gate z's for (batch=col, unit=16w+4q+r) -> gates are
// lane-local. gx folded in as MFMA C-initializer. h double-buffered in LDS (fp8).
// ONE barrier per step.
__global__ __launch_bounds__(1024, 4) void k_lstm(const unsigned char* __restrict__ w8_all,
                                                  const unsigned short* __restrict__ gx_all,
                                                  unsigned short* __restrict__ hcat) {
    const int d = blockIdx.x >> 2, bg = blockIdx.x & 3;
    const int tid = threadIdx.x, w = tid >> 6, l = tid & 63, quad = l >> 4, col = l & 15;
    const unsigned char* W = w8_all + (size_t)d * 262144;
    const unsigned short* G = gx_all + (size_t)d * 33554432;
    __shared__ __align__(16) unsigned char hld[2][16][272];   // 8704 B, pitch 272 (2-way max)

    // A-fragments: Wr[g][kt] = W[256g + 16w + col][kt*32 + quad*8 .. +7]  (fp8, 8B)
    long Wr[4][8];
    #pragma unroll
    for (int g = 0; g < 4; ++g)
        #pragma unroll
        for (int kt = 0; kt < 8; ++kt) {
            Wr[g][kt] = *(const long*)(W + (size_t)(256 * g + 16 * w + col) * 256 + kt * 32 + quad * 8);
            asm volatile("" : "+v"(Wr[g][kt]));   // pin: forbid remat/reload inside loop
        }
    for (int i = tid; i < 2176; i += 1024) ((unsigned int*)hld)[i] = 0;

    const int batch = bg * 16 + col;
    const int u0 = 16 * w + 4 * quad;                 // first of this lane's 4 units
    float cst[4] = {0.f, 0.f, 0.f, 0.f};

    const long gstride = d ? -131072 : 131072;        // bytes per t step in gx
    const long hstride = d ? -65536 : 65536;          // bytes per t step in hcat
    const char* gp = (const char*)(G + (size_t)batch * 1024 + u0) + (size_t)(d ? 511 : 0) * 131072;
    char* hp = (char*)(hcat + (size_t)batch * 512 + d * 256 + u0) + (size_t)(d ? 511 : 0) * 65536;

    // preload gx(t0) into C-init buffer
    uint2 gq[4];
    #pragma unroll
    for (int g = 0; g < 4; ++g) gq[g] = *(const uint2*)(gp + g * 512);
    gp += gstride;
    __syncthreads();

    #pragma clang loop unroll(disable)
    for (int step = 0; step < 512; ++step) {
        const int cur = step & 1;
        // C init = gx (z = W@h + gx accumulated by MFMA)
        floatx4 C[4];
        #pragma unroll
        for (int g = 0; g < 4; ++g) {
            C[g][0] = bf2f((unsigned short)(gq[g].x));
            C[g][1] = bf2f((unsigned short)(gq[g].x >> 16));
            C[g][2] = bf2f((unsigned short)(gq[g].y));
            C[g][3] = bf2f((unsigned short)(gq[g].y >> 16));
        }
        // B-fragments: h_fp8[batch=col][k = kt*32 + quad*8 .. +7]
        long Bf[8];
        #pragma unroll
        for (int kt = 0; kt < 8; ++kt)
            Bf[kt] = *(const long*)(&hld[cur][col][kt * 32 + quad * 8]);
        #pragma unroll
        for (int kt = 0; kt < 8; ++kt)
            #pragma unroll
            for (int g = 0; g < 4; ++g)
                C[g] = __builtin_amdgcn_mfma_f32_16x16x32_fp8_fp8(Wr[g][kt], Bf[kt], C[g], 0, 0, 0);
        // prefetch next step's gx early (covered by the gate-phase VALU below)
        #pragma unroll
        for (int g = 0; g < 4; ++g) gq[g] = *(const uint2*)(gp + g * 512);
        gp += gstride;
        // ---- lane-local gates: batch, units u0..u0+3 ----
        float hf[4];
        #pragma unroll
        for (int r = 0; r < 4; ++r) {
            float cc = sigm(C[1][r]) * cst[r] + sigm(C[0][r]) * tanh_(C[2][r]);
            cst[r] = cc;
            hf[r] = sigm(C[3][r]) * tanh_(cc);
        }
        uint2 hb;
        hb.x = (unsigned)f2bf_rz(hf[0]) | ((unsigned)f2bf_rz(hf[1]) << 16);
        hb.y = (unsigned)f2bf_rz(hf[2]) | ((unsigned)f2bf_rz(hf[3]) << 16);
        *(uint2*)hp = hb;
        hp += hstride;
        int pk = __builtin_amdgcn_cvt_pk_fp8_f32(hf[0], hf[1], 0, false);
        pk = __builtin_amdgcn_cvt_pk_fp8_f32(hf[2], hf[3], pk, true);
        *(unsigned int*)(&hld[cur ^ 1][col][u0]) = (unsigned int)pk;
        __syncthreads();
    }
}

// ---------------- scores = hcat @ w_fc.T + b_fc, fp32 [t][b][32] ----------------
__global__ __launch_bounds__(256, 4) void k_scores(const unsigned short* __restrict__ hcat,
                                                   const unsigned short* __restrict__ wfc,
                                                   const float* __restrict__ bfc,
                                                   float* __restrict__ sc) {
    const int tid = threadIdx.x, w = tid >> 6, l = tid & 63, quad = l >> 4, col = l & 15;
    const int m0 = blockIdx.x * 64 + w * 16;
    floatx4 C0 = (floatx4){0.f, 0.f, 0.f, 0.f}, C1 = C0;
    #pragma unroll
    for (int kt = 0; kt < 16; ++kt) {
        short8 A  = *(const short8*)(hcat + (size_t)(m0 + col) * 512 + kt * 32 + quad * 8);
        short8 B0 = *(const short8*)(wfc + (size_t)col * 512 + kt * 32 + quad * 8);
        short8 B1 = *(const short8*)(wfc + (size_t)(16 + col) * 512 + kt * 32 + quad * 8);
        C0 = __builtin_amdgcn_mfma_f32_16x16x32_bf16(A, B0, C0, 0, 0, 0);
        C1 = __builtin_amdgcn_mfma_f32_16x16x32_bf16(A, B1, C1, 0, 0, 0);
    }
    float b0 = bfc[col], b1 = bfc[16 + col];
    #pragma unroll
    for (int r = 0; r < 4; ++r) {
        int m = m0 + quad * 4 + r;
        sc[(size_t)m * 32 + col] = C0[r] + b0;
        sc[(size_t)m * 32 + 16 + col] = C1[r] + b1;
    }
}

// ---------------- CRF: true path score + forward algorithm, loss += total - true ----------------
__global__ __launch_bounds__(1024, 1) void k_crf(const float* __restrict__ sc, const int* __restrict__ tags,
                                                 const int* __restrict__ mask, const float* __restrict__ tr,
                                                 float* __restrict__ out) {
    __shared__ float Tm[32][33];
    __shared__ float alpha[32];
    __shared__ float trueb;
    const int b = blockIdx.x, tid = threadIdx.x;
    { int i = tid >> 5, j = tid & 31; Tm[i][j] = tr[tid]; }
    __syncthreads();
    if (tid < 64) {
        float acc = 0.f; int cnt = 0;
        for (int t = tid; t < 512; t += 64) cnt += mask[b * 512 + t];
        for (int t = tid + 1; t < 512; t += 64) {
            if (mask[b * 512 + t]) {
                int tg = tags[b * 512 + t], tp = tags[b * 512 + t - 1];
                acc += Tm[tp][tg] + sc[((size_t)t * 64 + b) * 32 + tg];
            }
        }
        #pragma unroll
        for (int m = 1; m < 64; m <<= 1) { acc += __shfl_xor(acc, m); cnt += __shfl_xor(cnt, m); }
        if (tid == 0) {
            int tg0 = tags[b * 512];
            float first = Tm[30][tg0] + sc[(size_t)b * 32 + tg0];
            int lt = tags[b * 512 + cnt - 1];
            trueb = first + acc + Tm[lt][31];
        }
    }
    if (tid < 32) alpha[tid] = Tm[30][tid] + sc[(size_t)b * 32 + tid];
    __syncthreads();
    const int j = tid >> 5, i = tid & 31;
    #pragma clang loop unroll(disable)
    for (int t = 1; t < 512; ++t) {
        float v = alpha[i] + Tm[i][j];
        float mx = v;
        #pragma unroll
        for (int m = 1; m < 32; m <<= 1) mx = fmaxf(mx, __shfl_xor(mx, m));
        float e = __expf(v - mx);
        #pragma unroll
        for (int m = 1; m < 32; m <<= 1) e += __shfl_xor(e, m);
        float nv = mx + __logf(e) + sc[((size_t)t * 64 + b) * 32 + j];
        int mk = mask[b * 512 + t];
        __syncthreads();
        if (mk && i == 0) alpha[j] = nv;
        __syncthreads();
    }
    if (tid < 32) {
        float v = alpha[tid] + Tm[tid][31];
        float mx = v;
        #pragma unroll
        for (int m = 1; m < 32; m <<= 1) mx = fmaxf(mx, __shfl_xor(mx, m));
        float e = __expf(v - mx);
        #pragma unroll
        for (int m = 1; m < 32; m <<= 1) e += __shfl_xor(e, m);
        if (tid == 0) atomicAdd(out, mx + __logf(e) - trueb);
    }
}

extern "C" void kernel_launch(void* const* d_in, const int* in_sizes, int n_in,
                              void* d_out, int out_size, void* d_ws, size_t ws_size,
                              hipStream_t stream) {
    const int* x      = (const int*)d_in[0];
    const int* tags   = (const int*)d_in[1];
    const int* mask   = (const int*)d_in[2];
    const float* emb  = (const float*)d_in[3];
    const float* wihf = (const float*)d_in[4];
    const float* whhf = (const float*)d_in[5];
    const float* bf_  = (const float*)d_in[6];
    const float* wihb = (const float*)d_in[7];
    const float* whhb = (const float*)d_in[8];
    const float* bb_  = (const float*)d_in[9];
    const float* wfc  = (const float*)d_in[10];
    const float* bfc  = (const float*)d_in[11];
    const float* tr   = (const float*)d_in[12];

    char* ws = (char*)d_ws;
    unsigned short* et   = (unsigned short*)(ws);                 //  16,777,216 B
    unsigned short* wbf  = (unsigned short*)(ws + 16777216);      //   1,064,960 B (wih f|b cat, then wfc @ elem 524288)
    unsigned char*  w8   = (unsigned char*)(ws + 17842176);      //     524,288 B (whh f|b fp8)
    unsigned short* gx   = (unsigned short*)(ws + 18366464);      // 134,217,728 B
    unsigned short* hcat = (unsigned short*)(ws + 152584192);     //  33,554,432 B
    float* sc            = (float*)(ws + 186138624);              //   4,194,304 B

    hipMemsetAsync(d_out, 0, sizeof(float), stream);
    k_cast_weights<<<2080, 256, 0, stream>>>(wihf, wihb, wfc, wbf);
    k_cast_fp8<<<1024, 256, 0, stream>>>(whhf, whhb, w8);
    k_gather<<<4096, 256, 0, stream>>>(x, emb, et);
    dim3 g2(256, 16);
    k_gx<<<g2, 256, 0, stream>>>(et, wbf, bf_, bb_, gx);
    k_lstm<<<8, 1024, 0, stream>>>(w8, gx, hcat);
    k_scores<<<512, 256, 0, stream>>>(hcat, wbf + 524288, bfc, sc);
    k_crf<<<64, 1024, 0, stream>>>(sc, tags, mask, tr, (float*)d_out);
}

// Round 7
// 1353.217 us; speedup vs baseline: 4.0687x; 1.0972x over previous
//
#include <hip/hip_runtime.h>

typedef __attribute__((ext_vector_type(8))) short short8;
typedef __attribute__((ext_vector_type(4))) float floatx4;

__device__ __forceinline__ float bf2f(unsigned short u) {
    union { unsigned int i; float f; } c; c.i = ((unsigned int)u) << 16; return c.f;
}
__device__ __forceinline__ unsigned short f2bf(float f) {
    union { float f; unsigned int i; } c; c.f = f;
    unsigned int u = c.i;
    return (unsigned short)((u + 0x7FFFu + ((u >> 16) & 1u)) >> 16);
}
__device__ __forceinline__ unsigned short f2bf_rz(float f) {
    union { float f; unsigned int i; } c; c.f = f;
    return (unsigned short)(c.i >> 16);
}
__device__ __forceinline__ float sigm(float x) {
    return __builtin_amdgcn_rcpf(1.f + __expf(-x));
}
__device__ __forceinline__ float tanh_(float x) {
    return 1.f - 2.f * __builtin_amdgcn_rcpf(1.f + __expf(2.f * x));
}

__device__ __forceinline__ void glds16(const void* g, void* l) {
    __builtin_amdgcn_global_load_lds((const __attribute__((address_space(1))) unsigned int*)g,
                                     (__attribute__((address_space(3))) unsigned int*)l, 16, 0, 0);
}

// ---------------- cast weights to bf16 (w_ih_f | w_ih_b | w_fc) ----------------
__global__ void k_cast_weights(const float* __restrict__ wihf, const float* __restrict__ wihb,
                               const float* __restrict__ wfc, unsigned short* __restrict__ dst) {
    int i = blockIdx.x * 256 + threadIdx.x;
    if (i >= 532480) return;
    float v;
    if (i < 262144) v = wihf[i];
    else if (i < 524288) v = wihb[i - 262144];
    else v = wfc[i - 524288];
    dst[i] = f2bf(v);
}

// ---------------- cast w_hh (f|b) to fp8 e4m3 ----------------
__global__ void k_cast_fp8(const float* __restrict__ whhf, const float* __restrict__ whhb,
                           unsigned char* __restrict__ dst) {
    int i = blockIdx.x * 256 + threadIdx.x;   // 262144 threads, 2 elems each
    if (i >= 262144) return;
    int e = i * 2;
    float a = (e < 262144) ? whhf[e] : whhb[e - 262144];
    float b = (e + 1 < 262144) ? whhf[e + 1] : whhb[e + 1 - 262144];
    int p = __builtin_amdgcn_cvt_pk_fp8_f32(a, b, 0, false);
    *(unsigned short*)(dst + e) = (unsigned short)(p & 0xffff);
}

// ---------------- embedding gather -> e_t[t*64+b][256] bf16 ----------------
__global__ void k_gather(const int* __restrict__ x, const float* __restrict__ emb,
                         unsigned short* __restrict__ et) {
    int id = blockIdx.x * 256 + threadIdx.x;   // 1,048,576 total
    int m = id >> 5, fi = (id & 31) << 3;
    int b = m & 63, t = m >> 6;
    int v = x[b * 512 + t];
    const float4* s = (const float4*)(emb + ((size_t)v << 8) + fi);
    float4 a = s[0], q = s[1];
    uint4 o;
    o.x = (unsigned)f2bf(a.x) | ((unsigned)f2bf(a.y) << 16);
    o.y = (unsigned)f2bf(a.z) | ((unsigned)f2bf(a.w) << 16);
    o.z = (unsigned)f2bf(q.x) | ((unsigned)f2bf(q.y) << 16);
    o.w = (unsigned)f2bf(q.z) | ((unsigned)f2bf(q.w) << 16);
    *(uint4*)(et + ((size_t)m << 8) + fi) = o;
}

// ---------------- gx = e @ w_ih.T + b, both dirs (N=2048), output bf16 [d][t][b][1024] ----------------
__global__ __launch_bounds__(256, 2) void k_gx(const unsigned short* __restrict__ et,
                                               const unsigned short* __restrict__ wcat,
                                               const float* __restrict__ bfv, const float* __restrict__ bbv,
                                               unsigned short* __restrict__ gx) {
    __shared__ unsigned short As[4096];
    __shared__ unsigned short Bs[4096];
    const int tid = threadIdx.x;
    const int w = tid >> 6, l = tid & 63, quad = l >> 4, col = l & 15;
    const size_t m0 = (size_t)blockIdx.x * 128, n0 = (size_t)blockIdx.y * 128;
    floatx4 C[4][4];
    #pragma unroll
    for (int i = 0; i < 4; ++i)
        #pragma unroll
        for (int j = 0; j < 4; ++j) C[i][j] = (floatx4){0.f, 0.f, 0.f, 0.f};
    const int srow = tid >> 2, scol = (tid & 3) * 16;
    for (int it = 0; it < 8; ++it) {
        const char* ga = (const char*)et + (m0 + srow) * 512 + it * 64 + scol;
        const char* gb = (const char*)wcat + (n0 + srow) * 512 + it * 64 + scol;
        glds16(ga,             (char*)As + w * 1024);
        glds16(ga + 64 * 512,  (char*)As + 4096 + w * 1024);
        glds16(gb,             (char*)Bs + w * 1024);
        glds16(gb + 64 * 512,  (char*)Bs + 4096 + w * 1024);
        __syncthreads();
        short8 Af[4], Bf[4];
        #pragma unroll
        for (int i = 0; i < 4; ++i) {
            Af[i] = *(const short8*)(As + (((w & 1) * 64 + i * 16 + col) * 32 + quad * 8));
            Bf[i] = *(const short8*)(Bs + (((w >> 1) * 64 + i * 16 + col) * 32 + quad * 8));
        }
        #pragma unroll
        for (int i = 0; i < 4; ++i)
            #pragma unroll
            for (int j = 0; j < 4; ++j)
                C[i][j] = __builtin_amdgcn_mfma_f32_16x16x32_bf16(Af[i], Bf[j], C[i][j], 0, 0, 0);
        __syncthreads();
    }
    const int mw = (w & 1) * 64, nw = (w >> 1) * 64;
    #pragma unroll
    for (int j = 0; j < 4; ++j) {
        int n = (int)n0 + nw + j * 16 + col;
        float bias = (n < 1024) ? bfv[n] : bbv[n - 1024];
        size_t dbase = (size_t)(n >> 10) * 33554432 + (size_t)(n & 1023);
        #pragma unroll
        for (int i = 0; i < 4; ++i)
            #pragma unroll
            for (int r = 0; r < 4; ++r) {
                size_t m = m0 + mw + i * 16 + quad * 4 + r;
                gx[dbase + m * 1024] = f2bf(C[i][j][r] + bias);
            }
    }
}

// ---------------- LSTM recurrence: 32 wgs = 2 dirs x 16 batch-groups of 4; 1024 thr ----------------
// fp8 MFMA K=32 (proven path, rounds 2-5): z = W(fp8, reg-resident) @ h(fp8, LDS).
// z -> zB (LDS, f32, b128 scatter). Gate phase: thread = (batch = tid>>8, unit = tid&255).
// B-tile replicates the 4 batches over 16 cols (col&3); only col<4 results scattered.
__global__ __launch_bounds__(1024, 4) void k_lstm(const unsigned char* __restrict__ w8_all,
                                                  const unsigned short* __restrict__ gx_all,
                                                  unsigned short* __restrict__ hcat) {
    const int d = blockIdx.x >> 4, bg = blockIdx.x & 15;
    const int tid = threadIdx.x, w = tid >> 6, l = tid & 63, quad = l >> 4, col = l & 15;
    const unsigned char* W = w8_all + (size_t)d * 262144;
    const unsigned short* G = gx_all + (size_t)d * 33554432;
    __shared__ __align__(16) float zB[4][4][260];          // 16,640 B  z[batch][gate][unit]
    __shared__ __align__(16) unsigned char hld[2][4][288]; //   2,304 B  h fp8 [batch][unit]

    // A-fragments: Wr[g][kt] = W[256g + 16w + col][kt*32 + quad*8 .. +7]  (fp8, 8B)
    long Wr[4][8];
    #pragma unroll
    for (int g = 0; g < 4; ++g)
        #pragma unroll
        for (int kt = 0; kt < 8; ++kt)
            Wr[g][kt] = *(const long*)(W + (size_t)(256 * g + 16 * w + col) * 256 + kt * 32 + quad * 8);
    for (int i = tid; i < 576; i += 1024) ((unsigned int*)hld)[i] = 0;

    const int batch = tid >> 8, j = tid & 255;             // gate-phase coords
    const int bglob = 4 * bg + batch;
    float cst = 0.f;
    const long gstep = d ? -65536 : 65536;                 // shorts per t in gx
    const long hstep = d ? -32768 : 32768;                 // shorts per t in hcat
    const unsigned short* gp = G + ((size_t)((d ? 511 : 0) * 64 + bglob) * 1024 + j);
    unsigned short* hp = hcat + ((size_t)((d ? 511 : 0) * 64 + bglob) * 512 + d * 256 + j);
    unsigned short gq0 = gp[0], gq1 = gp[256], gq2 = gp[512], gq3 = gp[768];
    gp += gstep;
    __syncthreads();

    #pragma clang loop unroll(disable)
    for (int step = 0; step < 512; ++step) {
        const int cur = step & 1;
        // ---- MFMA phase ----
        long Bf[8];
        #pragma unroll
        for (int kt = 0; kt < 8; ++kt)
            Bf[kt] = *(const long*)(&hld[cur][col & 3][kt * 32 + quad * 8]);
        floatx4 C[4];
        #pragma unroll
        for (int g = 0; g < 4; ++g) C[g] = (floatx4){0.f, 0.f, 0.f, 0.f};
        #pragma unroll
        for (int kt = 0; kt < 8; ++kt)
            #pragma unroll
            for (int g = 0; g < 4; ++g)
                C[g] = __builtin_amdgcn_mfma_f32_16x16x32_fp8_fp8(Wr[g][kt], Bf[kt], C[g], 0, 0, 0);
        if (col < 4) {
            #pragma unroll
            for (int g = 0; g < 4; ++g)
                *(floatx4*)(&zB[col][g][16 * w + 4 * quad]) = C[g];
        }
        __syncthreads();
        // ---- gate phase: (batch, unit j) ----
        float vi = zB[batch][0][j] + bf2f(gq0);
        float vf = zB[batch][1][j] + bf2f(gq1);
        float vg = zB[batch][2][j] + bf2f(gq2);
        float vo = zB[batch][3][j] + bf2f(gq3);
        // prefetch next step's gx (in flight across barrier + next MFMA phase)
        gq0 = gp[0]; gq1 = gp[256]; gq2 = gp[512]; gq3 = gp[768];
        gp += gstep;
        float cc = sigm(vf) * cst + sigm(vi) * tanh_(vg);
        cst = cc;
        float hf = sigm(vo) * tanh_(cc);
        *hp = f2bf_rz(hf);
        hp += hstep;
        int pk = __builtin_amdgcn_cvt_pk_fp8_f32(hf, hf, 0, false);
        hld[cur ^ 1][batch][j] = (unsigned char)(pk & 0xff);
        __syncthreads();
    }
}

// ---------------- scores = hcat @ w_fc.T + b_fc, fp32 [t][b][32] ----------------
__global__ __launch_bounds__(256, 4) void k_scores(const unsigned short* __restrict__ hcat,
                                                   const unsigned short* __restrict__ wfc,
                                                   const float* __restrict__ bfc,
                                                   float* __restrict__ sc) {
    const int tid = threadIdx.x, w = tid >> 6, l = tid & 63, quad = l >> 4, col = l & 15;
    const int m0 = blockIdx.x * 64 + w * 16;
    floatx4 C0 = (floatx4){0.f, 0.f, 0.f, 0.f}, C1 = C0;
    #pragma unroll
    for (int kt = 0; kt < 16; ++kt) {
        short8 A  = *(const short8*)(hcat + (size_t)(m0 + col) * 512 + kt * 32 + quad * 8);
        short8 B0 = *(const short8*)(wfc + (size_t)col * 512 + kt * 32 + quad * 8);
        short8 B1 = *(const short8*)(wfc + (size_t)(16 + col) * 512 + kt * 32 + quad * 8);
        C0 = __builtin_amdgcn_mfma_f32_16x16x32_bf16(A, B0, C0, 0, 0, 0);
        C1 = __builtin_amdgcn_mfma_f32_16x16x32_bf16(A, B1, C1, 0, 0, 0);
    }
    float b0 = bfc[col], b1 = bfc[16 + col];
    #pragma unroll
    for (int r = 0; r < 4; ++r) {
        int m = m0 + quad * 4 + r;
        sc[(size_t)m * 32 + col] = C0[r] + b0;
        sc[(size_t)m * 32 + 16 + col] = C1[r] + b1;
    }
}

// ---------------- CRF: true path score + forward algorithm, loss += total - true ----------------
__global__ __launch_bounds__(1024, 1) void k_crf(const float* __restrict__ sc, const int* __restrict__ tags,
                                                 const int* __restrict__ mask, const float* __restrict__ tr,
                                                 float* __restrict__ out) {
    __shared__ float Tm[32][33];
    __shared__ float alpha[32];
    __shared__ float trueb;
    const int b = blockIdx.x, tid = threadIdx.x;
    { int i = tid >> 5, j = tid & 31; Tm[i][j] = tr[tid]; }
    __syncthreads();
    if (tid < 64) {
        float acc = 0.f; int cnt = 0;
        for (int t = tid; t < 512; t += 64) cnt += mask[b * 512 + t];
        for (int t = tid + 1; t < 512; t += 64) {
            if (mask[b * 512 + t]) {
                int tg = tags[b * 512 + t], tp = tags[b * 512 + t - 1];
                acc += Tm[tp][tg] + sc[((size_t)t * 64 + b) * 32 + tg];
            }
        }
        #pragma unroll
        for (int m = 1; m < 64; m <<= 1) { acc += __shfl_xor(acc, m); cnt += __shfl_xor(cnt, m); }
        if (tid == 0) {
            int tg0 = tags[b * 512];
            float first = Tm[30][tg0] + sc[(size_t)b * 32 + tg0];
            int lt = tags[b * 512 + cnt - 1];
            trueb = first + acc + Tm[lt][31];
        }
    }
    if (tid < 32) alpha[tid] = Tm[30][tid] + sc[(size_t)b * 32 + tid];
    __syncthreads();
    const int j = tid >> 5, i = tid & 31;
    #pragma clang loop unroll(disable)
    for (int t = 1; t < 512; ++t) {
        float v = alpha[i] + Tm[i][j];
        float mx = v;
        #pragma unroll
        for (int m = 1; m < 32; m <<= 1) mx = fmaxf(mx, __shfl_xor(mx, m));
        float e = __expf(v - mx);
        #pragma unroll
        for (int m = 1; m < 32; m <<= 1) e += __shfl_xor(e, m);
        float nv = mx + __logf(e) + sc[((size_t)t * 64 + b) * 32 + j];
        int mk = mask[b * 512 + t];
        __syncthreads();
        if (mk && i == 0) alpha[j] = nv;
        __syncthreads();
    }
    if (tid < 32) {
        float v = alpha[tid] + Tm[tid][31];
        float mx = v;
        #pragma unroll
        for (int m = 1; m < 32; m <<= 1) mx = fmaxf(mx, __shfl_xor(mx, m));
        float e = __expf(v - mx);
        #pragma unroll
        for (int m = 1; m < 32; m <<= 1) e += __shfl_xor(e, m);
        if (tid == 0) atomicAdd(out, mx + __logf(e) - trueb);
    }
}

extern "C" void kernel_launch(void* const* d_in, const int* in_sizes, int n_in,
                              void* d_out, int out_size, void* d_ws, size_t ws_size,
                              hipStream_t stream) {
    const int* x      = (const int*)d_in[0];
    const int* tags   = (const int*)d_in[1];
    const int* mask   = (const int*)d_in[2];
    const float* emb  = (const float*)d_in[3];
    const float* wihf = (const float*)d_in[4];
    const float* whhf = (const float*)d_in[5];
    const float* bf_  = (const float*)d_in[6];
    const float* wihb = (const float*)d_in[7];
    const float* whhb = (const float*)d_in[8];
    const float* bb_  = (const float*)d_in[9];
    const float* wfc  = (const float*)d_in[10];
    const float* bfc  = (const float*)d_in[11];
    const float* tr   = (const float*)d_in[12];

    char* ws = (char*)d_ws;
    unsigned short* et   = (unsigned short*)(ws);                 //  16,777,216 B
    unsigned short* wbf  = (unsigned short*)(ws + 16777216);      //   1,064,960 B (wih f|b cat, then wfc @ elem 524288)
    unsigned char*  w8   = (unsigned char*)(ws + 17842176);      //     524,288 B (whh f|b fp8)
    unsigned short* gx   = (unsigned short*)(ws + 18366464);      // 134,217,728 B
    unsigned short* hcat = (unsigned short*)(ws + 152584192);     //  33,554,432 B
    float* sc            = (float*)(ws + 186138624);              //   4,194,304 B

    hipMemsetAsync(d_out, 0, sizeof(float), stream);
    k_cast_weights<<<2080, 256, 0, stream>>>(wihf, wihb, wfc, wbf);
    k_cast_fp8<<<1024, 256, 0, stream>>>(whhf, whhb, w8);
    k_gather<<<4096, 256, 0, stream>>>(x, emb, et);
    dim3 g2(256, 16);
    k_gx<<<g2, 256, 0, stream>>>(et, wbf, bf_, bb_, gx);
    k_lstm<<<32, 1024, 0, stream>>>(w8, gx, hcat);
    k_scores<<<512, 256, 0, stream>>>(hcat, wbf + 524288, bfc, sc);
    k_crf<<<64, 1024, 0, stream>>>(sc, tags, mask, tr, (float*)d_out);
}

// Round 8
// 1089.696 us; speedup vs baseline: 5.0527x; 1.2418x over previous
//
#include <hip/hip_runtime.h>

typedef __attribute__((ext_vector_type(8))) short short8;
typedef __attribute__((ext_vector_type(4))) float floatx4;
typedef __attribute__((ext_vector_type(8))) int int8v;

__device__ __forceinline__ float bf2f(unsigned short u) {
    union { unsigned int i; float f; } c; c.i = ((unsigned int)u) << 16; return c.f;
}
__device__ __forceinline__ unsigned short f2bf(float f) {
    union { float f; unsigned int i; } c; c.f = f;
    unsigned int u = c.i;
    return (unsigned short)((u + 0x7FFFu + ((u >> 16) & 1u)) >> 16);
}
__device__ __forceinline__ unsigned short f2bf_rz(float f) {
    union { float f; unsigned int i; } c; c.f = f;
    return (unsigned short)(c.i >> 16);
}
__device__ __forceinline__ float sigm(float x) {
    return __builtin_amdgcn_rcpf(1.f + __expf(-x));
}
__device__ __forceinline__ float tanh_(float x) {
    return 1.f - 2.f * __builtin_amdgcn_rcpf(1.f + __expf(2.f * x));
}

__device__ __forceinline__ void glds16(const void* g, void* l) {
    __builtin_amdgcn_global_load_lds((const __attribute__((address_space(1))) unsigned int*)g,
                                     (__attribute__((address_space(3))) unsigned int*)l, 16, 0, 0);
}

// ---------------- cast weights to bf16 (w_ih_f | w_ih_b | w_fc) ----------------
__global__ void k_cast_weights(const float* __restrict__ wihf, const float* __restrict__ wihb,
                               const float* __restrict__ wfc, unsigned short* __restrict__ dst) {
    int i = blockIdx.x * 256 + threadIdx.x;
    if (i >= 532480) return;
    float v;
    if (i < 262144) v = wihf[i];
    else if (i < 524288) v = wihb[i - 262144];
    else v = wfc[i - 524288];
    dst[i] = f2bf(v);
}

// ---------------- cast w_hh (f|b) to fp8 e4m3 ----------------
__global__ void k_cast_fp8(const float* __restrict__ whhf, const float* __restrict__ whhb,
                           unsigned char* __restrict__ dst) {
    int i = blockIdx.x * 256 + threadIdx.x;   // 262144 threads, 2 elems each
    if (i >= 262144) return;
    int e = i * 2;
    float a = (e < 262144) ? whhf[e] : whhb[e - 262144];
    float b = (e + 1 < 262144) ? whhf[e + 1] : whhb[e + 1 - 262144];
    int p = __builtin_amdgcn_cvt_pk_fp8_f32(a, b, 0, false);
    *(unsigned short*)(dst + e) = (unsigned short)(p & 0xffff);
}

// ---------------- embedding gather -> e_t[t*64+b][256] bf16 ----------------
__global__ void k_gather(const int* __restrict__ x, const float* __restrict__ emb,
                         unsigned short* __restrict__ et) {
    int id = blockIdx.x * 256 + threadIdx.x;   // 1,048,576 total
    int m = id >> 5, fi = (id & 31) << 3;
    int b = m & 63, t = m >> 6;
    int v = x[b * 512 + t];
    const float4* s = (const float4*)(emb + ((size_t)v << 8) + fi);
    float4 a = s[0], q = s[1];
    uint4 o;
    o.x = (unsigned)f2bf(a.x) | ((unsigned)f2bf(a.y) << 16);
    o.y = (unsigned)f2bf(a.z) | ((unsigned)f2bf(a.w) << 16);
    o.z = (unsigned)f2bf(q.x) | ((unsigned)f2bf(q.y) << 16);
    o.w = (unsigned)f2bf(q.z) | ((unsigned)f2bf(q.w) << 16);
    *(uint4*)(et + ((size_t)m << 8) + fi) = o;
}

// ---------------- gx = e @ w_ih.T + b, both dirs (N=2048), output bf16 [d][t][b][1024] ----------------
__global__ __launch_bounds__(256, 2) void k_gx(const unsigned short* __restrict__ et,
                                               const unsigned short* __restrict__ wcat,
                                               const float* __restrict__ bfv, const float* __restrict__ bbv,
                                               unsigned short* __restrict__ gx) {
    __shared__ unsigned short As[4096];
    __shared__ unsigned short Bs[4096];
    const int tid = threadIdx.x;
    const int w = tid >> 6, l = tid & 63, quad = l >> 4, col = l & 15;
    const size_t m0 = (size_t)blockIdx.x * 128, n0 = (size_t)blockIdx.y * 128;
    floatx4 C[4][4];
    #pragma unroll
    for (int i = 0; i < 4; ++i)
        #pragma unroll
        for (int j = 0; j < 4; ++j) C[i][j] = (floatx4){0.f, 0.f, 0.f, 0.f};
    const int srow = tid >> 2, scol = (tid & 3) * 16;
    for (int it = 0; it < 8; ++it) {
        const char* ga = (const char*)et + (m0 + srow) * 512 + it * 64 + scol;
        const char* gb = (const char*)wcat + (n0 + srow) * 512 + it * 64 + scol;
        glds16(ga,             (char*)As + w * 1024);
        glds16(ga + 64 * 512,  (char*)As + 4096 + w * 1024);
        glds16(gb,             (char*)Bs + w * 1024);
        glds16(gb + 64 * 512,  (char*)Bs + 4096 + w * 1024);
        __syncthreads();
        short8 Af[4], Bf[4];
        #pragma unroll
        for (int i = 0; i < 4; ++i) {
            Af[i] = *(const short8*)(As + (((w & 1) * 64 + i * 16 + col) * 32 + quad * 8));
            Bf[i] = *(const short8*)(Bs + (((w >> 1) * 64 + i * 16 + col) * 32 + quad * 8));
        }
        #pragma unroll
        for (int i = 0; i < 4; ++i)
            #pragma unroll
            for (int j = 0; j < 4; ++j)
                C[i][j] = __builtin_amdgcn_mfma_f32_16x16x32_bf16(Af[i], Bf[j], C[i][j], 0, 0, 0);
        __syncthreads();
    }
    const int mw = (w & 1) * 64, nw = (w >> 1) * 64;
    #pragma unroll
    for (int j = 0; j < 4; ++j) {
        int n = (int)n0 + nw + j * 16 + col;
        float bias = (n < 1024) ? bfv[n] : bbv[n - 1024];
        size_t dbase = (size_t)(n >> 10) * 33554432 + (size_t)(n & 1023);
        #pragma unroll
        for (int i = 0; i < 4; ++i)
            #pragma unroll
            for (int r = 0; r < 4; ++r) {
                size_t m = m0 + mw + i * 16 + quad * 4 + r;
                gx[dbase + m * 1024] = f2bf(C[i][j][r] + bias);
            }
    }
}

// ---------------- LSTM recurrence: 32 wgs = 2 dirs x 16 batch-groups of 4; 1024 thr ----------------
// MX-scaled fp8 MFMA K=128, unit scales (E8M0 0x7F = 1.0): numerically identical to the
// round-7 fp8 K=32 path, at 2x MFMA rate. W reg-resident (64 VGPR), h fp8 in LDS.
// z -> zB (LDS, f32, b128 scatter). Gate phase: thread = (batch = tid>>8, unit = tid&255).
__global__ __launch_bounds__(1024, 4) void k_lstm(const unsigned char* __restrict__ w8_all,
                                                  const unsigned short* __restrict__ gx_all,
                                                  unsigned short* __restrict__ hcat) {
    const int d = blockIdx.x >> 4, bg = blockIdx.x & 15;
    const int tid = threadIdx.x, w = tid >> 6, l = tid & 63, quad = l >> 4, col = l & 15;
    const unsigned char* W = w8_all + (size_t)d * 262144;
    const unsigned short* G = gx_all + (size_t)d * 33554432;
    __shared__ __align__(16) float zB[4][4][260];          // 16,640 B  z[batch][gate][unit]
    __shared__ __align__(16) unsigned char hld[2][4][288]; //   2,304 B  h fp8 [batch][unit]

    // A-fragments: Wr[g][kt] = W[256g + 16w + col][kt*128 + quad*32 .. +31]  (fp8, 32B)
    int8v Wr[4][2];
    #pragma unroll
    for (int g = 0; g < 4; ++g)
        #pragma unroll
        for (int kt = 0; kt < 2; ++kt)
            Wr[g][kt] = *(const int8v*)(W + (size_t)(256 * g + 16 * w + col) * 256 + kt * 128 + quad * 32);
    for (int i = tid; i < 576; i += 1024) ((unsigned int*)hld)[i] = 0;

    const int batch = tid >> 8, j = tid & 255;             // gate-phase coords
    const int bglob = 4 * bg + batch;
    float cst = 0.f;
    const long gstep = d ? -65536 : 65536;                 // shorts per t in gx
    const long hstep = d ? -32768 : 32768;                 // shorts per t in hcat
    const unsigned short* gp = G + ((size_t)((d ? 511 : 0) * 64 + bglob) * 1024 + j);
    unsigned short* hp = hcat + ((size_t)((d ? 511 : 0) * 64 + bglob) * 512 + d * 256 + j);
    unsigned short gq0 = gp[0], gq1 = gp[256], gq2 = gp[512], gq3 = gp[768];
    gp += gstep;
    __syncthreads();

    #pragma clang loop unroll(disable)
    for (int step = 0; step < 512; ++step) {
        const int cur = step & 1;
        // ---- MFMA phase (K=128 x 2) ----
        int8v Bf[2];
        #pragma unroll
        for (int kt = 0; kt < 2; ++kt)
            Bf[kt] = *(const int8v*)(&hld[cur][col & 3][kt * 128 + quad * 32]);
        floatx4 C[4];
        #pragma unroll
        for (int g = 0; g < 4; ++g) C[g] = (floatx4){0.f, 0.f, 0.f, 0.f};
        #pragma unroll
        for (int kt = 0; kt < 2; ++kt)
            #pragma unroll
            for (int g = 0; g < 4; ++g)
                C[g] = __builtin_amdgcn_mfma_scale_f32_16x16x128_f8f6f4(
                    Wr[g][kt], Bf[kt], C[g], 0, 0, 0, 0x7f7f7f7f, 0, 0x7f7f7f7f);
        if (col < 4) {
            #pragma unroll
            for (int g = 0; g < 4; ++g)
                *(floatx4*)(&zB[col][g][16 * w + 4 * quad]) = C[g];
        }
        __syncthreads();
        // ---- gate phase: (batch, unit j) ----
        float vi = zB[batch][0][j] + bf2f(gq0);
        float vf = zB[batch][1][j] + bf2f(gq1);
        float vg = zB[batch][2][j] + bf2f(gq2);
        float vo = zB[batch][3][j] + bf2f(gq3);
        // prefetch next step's gx (in flight across barrier + next MFMA phase)
        gq0 = gp[0]; gq1 = gp[256]; gq2 = gp[512]; gq3 = gp[768];
        gp += gstep;
        float cc = sigm(vf) * cst + sigm(vi) * tanh_(vg);
        cst = cc;
        float hf = sigm(vo) * tanh_(cc);
        *hp = f2bf_rz(hf);
        hp += hstep;
        int pk = __builtin_amdgcn_cvt_pk_fp8_f32(hf, hf, 0, false);
        hld[cur ^ 1][batch][j] = (unsigned char)(pk & 0xff);
        __syncthreads();
    }
}

// ---------------- scores = hcat @ w_fc.T + b_fc, fp32 [t][b][32] ----------------
__global__ __launch_bounds__(256, 4) void k_scores(const unsigned short* __restrict__ hcat,
                                                   const unsigned short* __restrict__ wfc,
                                                   const float* __restrict__ bfc,
                                                   float* __restrict__ sc) {
    const int tid = threadIdx.x, w = tid >> 6, l = tid & 63, quad = l >> 4, col = l & 15;
    const int m0 = blockIdx.x * 64 + w * 16;
    floatx4 C0 = (floatx4){0.f, 0.f, 0.f, 0.f}, C1 = C0;
    #pragma unroll
    for (int kt = 0; kt < 16; ++kt) {
        short8 A  = *(const short8*)(hcat + (size_t)(m0 + col) * 512 + kt * 32 + quad * 8);
        short8 B0 = *(const short8*)(wfc + (size_t)col * 512 + kt * 32 + quad * 8);
        short8 B1 = *(const short8*)(wfc + (size_t)(16 + col) * 512 + kt * 32 + quad * 8);
        C0 = __builtin_amdgcn_mfma_f32_16x16x32_bf16(A, B0, C0, 0, 0, 0);
        C1 = __builtin_amdgcn_mfma_f32_16x16x32_bf16(A, B1, C1, 0, 0, 0);
    }
    float b0 = bfc[col], b1 = bfc[16 + col];
    #pragma unroll
    for (int r = 0; r < 4; ++r) {
        int m = m0 + quad * 4 + r;
        sc[(size_t)m * 32 + col] = C0[r] + b0;
        sc[(size_t)m * 32 + 16 + col] = C1[r] + b1;
    }
}

// ---------------- CRF: true path score + forward algorithm, loss += total - true ----------------
__global__ __launch_bounds__(1024, 1) void k_crf(const float* __restrict__ sc, const int* __restrict__ tags,
                                                 const int* __restrict__ mask, const float* __restrict__ tr,
                                                 float* __restrict__ out) {
    __shared__ float Tm[32][33];
    __shared__ float alpha[32];
    __shared__ float trueb;
    const int b = blockIdx.x, tid = threadIdx.x;
    { int i = tid >> 5, j = tid & 31; Tm[i][j] = tr[tid]; }
    __syncthreads();
    if (tid < 64) {
        float acc = 0.f; int cnt = 0;
        for (int t = tid; t < 512; t += 64) cnt += mask[b * 512 + t];
        for (int t = tid + 1; t < 512; t += 64) {
            if (mask[b * 512 + t]) {
                int tg = tags[b * 512 + t], tp = tags[b * 512 + t - 1];
                acc += Tm[tp][tg] + sc[((size_t)t * 64 + b) * 32 + tg];
            }
        }
        #pragma unroll
        for (int m = 1; m < 64; m <<= 1) { acc += __shfl_xor(acc, m); cnt += __shfl_xor(cnt, m); }
        if (tid == 0) {
            int tg0 = tags[b * 512];
            float first = Tm[30][tg0] + sc[(size_t)b * 32 + tg0];
            int lt = tags[b * 512 + cnt - 1];
            trueb = first + acc + Tm[lt][31];
        }
    }
    if (tid < 32) alpha[tid] = Tm[30][tid] + sc[(size_t)b * 32 + tid];
    __syncthreads();
    const int j = tid >> 5, i = tid & 31;
    #pragma clang loop unroll(disable)
    for (int t = 1; t < 512; ++t) {
        float v = alpha[i] + Tm[i][j];
        float mx = v;
        #pragma unroll
        for (int m = 1; m < 32; m <<= 1) mx = fmaxf(mx, __shfl_xor(mx, m));
        float e = __expf(v - mx);
        #pragma unroll
        for (int m = 1; m < 32; m <<= 1) e += __shfl_xor(e, m);
        float nv = mx + __logf(e) + sc[((size_t)t * 64 + b) * 32 + j];
        int mk = mask[b * 512 + t];
        __syncthreads();
        if (mk && i == 0) alpha[j] = nv;
        __syncthreads();
    }
    if (tid < 32) {
        float v = alpha[tid] + Tm[tid][31];
        float mx = v;
        #pragma unroll
        for (int m = 1; m < 32; m <<= 1) mx = fmaxf(mx, __shfl_xor(mx, m));
        float e = __expf(v - mx);
        #pragma unroll
        for (int m = 1; m < 32; m <<= 1) e += __shfl_xor(e, m);
        if (tid == 0) atomicAdd(out, mx + __logf(e) - trueb);
    }
}

extern "C" void kernel_launch(void* const* d_in, const int* in_sizes, int n_in,
                              void* d_out, int out_size, void* d_ws, size_t ws_size,
                              hipStream_t stream) {
    const int* x      = (const int*)d_in[0];
    const int* tags   = (const int*)d_in[1];
    const int* mask   = (const int*)d_in[2];
    const float* emb  = (const float*)d_in[3];
    const float* wihf = (const float*)d_in[4];
    const float* whhf = (const float*)d_in[5];
    const float* bf_  = (const float*)d_in[6];
    const float* wihb = (const float*)d_in[7];
    const float* whhb = (const float*)d_in[8];
    const float* bb_  = (const float*)d_in[9];
    const float* wfc  = (const float*)d_in[10];
    const float* bfc  = (const float*)d_in[11];
    const float* tr   = (const float*)d_in[12];

    char* ws = (char*)d_ws;
    unsigned short* et   = (unsigned short*)(ws);                 //  16,777,216 B
    unsigned short* wbf  = (unsigned short*)(ws + 16777216);      //   1,064,960 B (wih f|b cat, then wfc @ elem 524288)
    unsigned char*  w8   = (unsigned char*)(ws + 17842176);      //     524,288 B (whh f|b fp8)
    unsigned short* gx   = (unsigned short*)(ws + 18366464);      // 134,217,728 B
    unsigned short* hcat = (unsigned short*)(ws + 152584192);     //  33,554,432 B
    float* sc            = (float*)(ws + 186138624);              //   4,194,304 B

    hipMemsetAsync(d_out, 0, sizeof(float), stream);
    k_cast_weights<<<2080, 256, 0, stream>>>(wihf, wihb, wfc, wbf);
    k_cast_fp8<<<1024, 256, 0, stream>>>(whhf, whhb, w8);
    k_gather<<<4096, 256, 0, stream>>>(x, emb, et);
    dim3 g2(256, 16);
    k_gx<<<g2, 256, 0, stream>>>(et, wbf, bf_, bb_, gx);
    k_lstm<<<32, 1024, 0, stream>>>(w8, gx, hcat);
    k_scores<<<512, 256, 0, stream>>>(hcat, wbf + 524288, bfc, sc);
    k_crf<<<64, 1024, 0, stream>>>(sc, tags, mask, tr, (float*)d_out);
}

// Round 9
// 1049.256 us; speedup vs baseline: 5.2474x; 1.0385x over previous
//
#include <hip/hip_runtime.h>

typedef __attribute__((ext_vector_type(8))) short short8;
typedef __attribute__((ext_vector_type(4))) float floatx4;
typedef __attribute__((ext_vector_type(8))) int int8v;

__device__ __forceinline__ float bf2f(unsigned short u) {
    union { unsigned int i; float f; } c; c.i = ((unsigned int)u) << 16; return c.f;
}
__device__ __forceinline__ unsigned short f2bf(float f) {
    union { float f; unsigned int i; } c; c.f = f;
    unsigned int u = c.i;
    return (unsigned short)((u + 0x7FFFu + ((u >> 16) & 1u)) >> 16);
}
__device__ __forceinline__ unsigned short f2bf_rz(float f) {
    union { float f; unsigned int i; } c; c.f = f;
    return (unsigned short)(c.i >> 16);
}
__device__ __forceinline__ float sigm(float x) {
    return __builtin_amdgcn_rcpf(1.f + __expf(-x));
}
__device__ __forceinline__ float tanh_(float x) {
    return 1.f - 2.f * __builtin_amdgcn_rcpf(1.f + __expf(2.f * x));
}

__device__ __forceinline__ void glds16(const void* g, void* l) {
    __builtin_amdgcn_global_load_lds((const __attribute__((address_space(1))) unsigned int*)g,
                                     (__attribute__((address_space(3))) unsigned int*)l, 16, 0, 0);
}

// ---------------- cast weights to bf16 (w_ih_f | w_ih_b | w_fc) ----------------
__global__ void k_cast_weights(const float* __restrict__ wihf, const float* __restrict__ wihb,
                               const float* __restrict__ wfc, unsigned short* __restrict__ dst) {
    int i = blockIdx.x * 256 + threadIdx.x;
    if (i >= 532480) return;
    float v;
    if (i < 262144) v = wihf[i];
    else if (i < 524288) v = wihb[i - 262144];
    else v = wfc[i - 524288];
    dst[i] = f2bf(v);
}

// ---------------- cast w_hh (f|b) to fp8 e4m3 ----------------
__global__ void k_cast_fp8(const float* __restrict__ whhf, const float* __restrict__ whhb,
                           unsigned char* __restrict__ dst) {
    int i = blockIdx.x * 256 + threadIdx.x;   // 262144 threads, 2 elems each
    if (i >= 262144) return;
    int e = i * 2;
    float a = (e < 262144) ? whhf[e] : whhb[e - 262144];
    float b = (e + 1 < 262144) ? whhf[e + 1] : whhb[e + 1 - 262144];
    int p = __builtin_amdgcn_cvt_pk_fp8_f32(a, b, 0, false);
    *(unsigned short*)(dst + e) = (unsigned short)(p & 0xffff);
}

// ---------------- embedding gather -> e_t[t*64+b][256] bf16 ----------------
__global__ void k_gather(const int* __restrict__ x, const float* __restrict__ emb,
                         unsigned short* __restrict__ et) {
    int id = blockIdx.x * 256 + threadIdx.x;   // 1,048,576 total
    int m = id >> 5, fi = (id & 31) << 3;
    int b = m & 63, t = m >> 6;
    int v = x[b * 512 + t];
    const float4* s = (const float4*)(emb + ((size_t)v << 8) + fi);
    float4 a = s[0], q = s[1];
    uint4 o;
    o.x = (unsigned)f2bf(a.x) | ((unsigned)f2bf(a.y) << 16);
    o.y = (unsigned)f2bf(a.z) | ((unsigned)f2bf(a.w) << 16);
    o.z = (unsigned)f2bf(q.x) | ((unsigned)f2bf(q.y) << 16);
    o.w = (unsigned)f2bf(q.z) | ((unsigned)f2bf(q.w) << 16);
    *(uint4*)(et + ((size_t)m << 8) + fi) = o;
}

// ---------------- gx = e @ w_ih.T + b, both dirs (N=2048), output bf16 [d][t][b][1024] ----------------
__global__ __launch_bounds__(256, 2) void k_gx(const unsigned short* __restrict__ et,
                                               const unsigned short* __restrict__ wcat,
                                               const float* __restrict__ bfv, const float* __restrict__ bbv,
                                               unsigned short* __restrict__ gx) {
    __shared__ unsigned short As[4096];
    __shared__ unsigned short Bs[4096];
    const int tid = threadIdx.x;
    const int w = tid >> 6, l = tid & 63, quad = l >> 4, col = l & 15;
    const size_t m0 = (size_t)blockIdx.x * 128, n0 = (size_t)blockIdx.y * 128;
    floatx4 C[4][4];
    #pragma unroll
    for (int i = 0; i < 4; ++i)
        #pragma unroll
        for (int j = 0; j < 4; ++j) C[i][j] = (floatx4){0.f, 0.f, 0.f, 0.f};
    const int srow = tid >> 2, scol = (tid & 3) * 16;
    for (int it = 0; it < 8; ++it) {
        const char* ga = (const char*)et + (m0 + srow) * 512 + it * 64 + scol;
        const char* gb = (const char*)wcat + (n0 + srow) * 512 + it * 64 + scol;
        glds16(ga,             (char*)As + w * 1024);
        glds16(ga + 64 * 512,  (char*)As + 4096 + w * 1024);
        glds16(gb,             (char*)Bs + w * 1024);
        glds16(gb + 64 * 512,  (char*)Bs + 4096 + w * 1024);
        __syncthreads();
        short8 Af[4], Bf[4];
        #pragma unroll
        for (int i = 0; i < 4; ++i) {
            Af[i] = *(const short8*)(As + (((w & 1) * 64 + i * 16 + col) * 32 + quad * 8));
            Bf[i] = *(const short8*)(Bs + (((w >> 1) * 64 + i * 16 + col) * 32 + quad * 8));
        }
        #pragma unroll
        for (int i = 0; i < 4; ++i)
            #pragma unroll
            for (int j = 0; j < 4; ++j)
                C[i][j] = __builtin_amdgcn_mfma_f32_16x16x32_bf16(Af[i], Bf[j], C[i][j], 0, 0, 0);
        __syncthreads();
    }
    const int mw = (w & 1) * 64, nw = (w >> 1) * 64;
    #pragma unroll
    for (int j = 0; j < 4; ++j) {
        int n = (int)n0 + nw + j * 16 + col;
        float bias = (n < 1024) ? bfv[n] : bbv[n - 1024];
        size_t dbase = (size_t)(n >> 10) * 33554432 + (size_t)(n & 1023);
        #pragma unroll
        for (int i = 0; i < 4; ++i)
            #pragma unroll
            for (int r = 0; r < 4; ++r) {
                size_t m = m0 + mw + i * 16 + quad * 4 + r;
                gx[dbase + m * 1024] = f2bf(C[i][j][r] + bias);
            }
    }
}

// ---------------- LSTM recurrence: 64 wgs = 2 dirs x 32 batch-groups of 2; 512 thr (8 waves) ----
// MX-scaled fp8 K=128, unit scales. Wave w covers units [32w, 32w+32) for all 4 gates:
// A-frags Wr[g][ut][kt], 128 VGPR. B-tile replicates 2 batches over 16 cols (col&1).
// z -> zB (LDS f32). Gate phase: thread = (batch = tid>>8, unit = tid&255). 2 barriers/step.
__global__ __launch_bounds__(512, 2) void k_lstm(const unsigned char* __restrict__ w8_all,
                                                 const unsigned short* __restrict__ gx_all,
                                                 unsigned short* __restrict__ hcat) {
    const int d = blockIdx.x >> 5, bg = blockIdx.x & 31;
    const int tid = threadIdx.x, w = tid >> 6, l = tid & 63, quad = l >> 4, col = l & 15;
    const unsigned char* W = w8_all + (size_t)d * 262144;
    const unsigned short* G = gx_all + (size_t)d * 33554432;
    __shared__ __align__(16) float zB[2][4][260];          // 8,320 B  z[batch][gate][unit]
    __shared__ __align__(16) unsigned char hld[2][2][288]; // 1,152 B  h fp8 [batch][unit]

    // A-fragments: Wr[g][ut][kt] = W[256g + 32w + 16ut + col][kt*128 + quad*32 .. +31]
    int8v Wr[4][2][2];
    #pragma unroll
    for (int g = 0; g < 4; ++g)
        #pragma unroll
        for (int ut = 0; ut < 2; ++ut)
            #pragma unroll
            for (int kt = 0; kt < 2; ++kt)
                Wr[g][ut][kt] = *(const int8v*)(W + (size_t)(256 * g + 32 * w + 16 * ut + col) * 256
                                                + kt * 128 + quad * 32);
    for (int i = tid; i < 288; i += 512) ((unsigned int*)hld)[i] = 0;

    const int batch = tid >> 8, j = tid & 255;             // gate-phase coords
    const int bglob = 2 * bg + batch;
    float cst = 0.f;
    const long gstep = d ? -65536 : 65536;                 // shorts per t in gx
    const long hstep = d ? -32768 : 32768;                 // shorts per t in hcat
    const unsigned short* gp = G + ((size_t)((d ? 511 : 0) * 64 + bglob) * 1024 + j);
    unsigned short* hp = hcat + ((size_t)((d ? 511 : 0) * 64 + bglob) * 512 + d * 256 + j);
    unsigned short gq0 = gp[0], gq1 = gp[256], gq2 = gp[512], gq3 = gp[768];
    gp += gstep;
    __syncthreads();

    #pragma clang loop unroll(disable)
    for (int step = 0; step < 512; ++step) {
        const int cur = step & 1;
        // ---- MFMA phase (K=128 x 2) ----
        int8v Bf[2];
        #pragma unroll
        for (int kt = 0; kt < 2; ++kt)
            Bf[kt] = *(const int8v*)(&hld[cur][col & 1][kt * 128 + quad * 32]);
        floatx4 C[4][2];
        #pragma unroll
        for (int g = 0; g < 4; ++g)
            #pragma unroll
            for (int ut = 0; ut < 2; ++ut) C[g][ut] = (floatx4){0.f, 0.f, 0.f, 0.f};
        #pragma unroll
        for (int kt = 0; kt < 2; ++kt)
            #pragma unroll
            for (int g = 0; g < 4; ++g)
                #pragma unroll
                for (int ut = 0; ut < 2; ++ut)
                    C[g][ut] = __builtin_amdgcn_mfma_scale_f32_16x16x128_f8f6f4(
                        Wr[g][ut][kt], Bf[kt], C[g][ut], 0, 0, 0, 0x7f7f7f7f, 0, 0x7f7f7f7f);
        if (col < 2) {
            #pragma unroll
            for (int g = 0; g < 4; ++g)
                #pragma unroll
                for (int ut = 0; ut < 2; ++ut)
                    *(floatx4*)(&zB[col][g][32 * w + 16 * ut + 4 * quad]) = C[g][ut];
        }
        __syncthreads();
        // ---- gate phase: (batch, unit j) ----
        float vi = zB[batch][0][j] + bf2f(gq0);
        float vf = zB[batch][1][j] + bf2f(gq1);
        float vg = zB[batch][2][j] + bf2f(gq2);
        float vo = zB[batch][3][j] + bf2f(gq3);
        // prefetch next step's gx (in flight across barrier + next MFMA phase)
        gq0 = gp[0]; gq1 = gp[256]; gq2 = gp[512]; gq3 = gp[768];
        gp += gstep;
        float cc = sigm(vf) * cst + sigm(vi) * tanh_(vg);
        cst = cc;
        float hf = sigm(vo) * tanh_(cc);
        *hp = f2bf_rz(hf);
        hp += hstep;
        int pk = __builtin_amdgcn_cvt_pk_fp8_f32(hf, hf, 0, false);
        hld[cur ^ 1][batch][j] = (unsigned char)(pk & 0xff);
        __syncthreads();
    }
}

// ---------------- scores = hcat @ w_fc.T + b_fc, fp32 [t][b][32] ----------------
__global__ __launch_bounds__(256, 4) void k_scores(const unsigned short* __restrict__ hcat,
                                                   const unsigned short* __restrict__ wfc,
                                                   const float* __restrict__ bfc,
                                                   float* __restrict__ sc) {
    const int tid = threadIdx.x, w = tid >> 6, l = tid & 63, quad = l >> 4, col = l & 15;
    const int m0 = blockIdx.x * 64 + w * 16;
    floatx4 C0 = (floatx4){0.f, 0.f, 0.f, 0.f}, C1 = C0;
    #pragma unroll
    for (int kt = 0; kt < 16; ++kt) {
        short8 A  = *(const short8*)(hcat + (size_t)(m0 + col) * 512 + kt * 32 + quad * 8);
        short8 B0 = *(const short8*)(wfc + (size_t)col * 512 + kt * 32 + quad * 8);
        short8 B1 = *(const short8*)(wfc + (size_t)(16 + col) * 512 + kt * 32 + quad * 8);
        C0 = __builtin_amdgcn_mfma_f32_16x16x32_bf16(A, B0, C0, 0, 0, 0);
        C1 = __builtin_amdgcn_mfma_f32_16x16x32_bf16(A, B1, C1, 0, 0, 0);
    }
    float b0 = bfc[col], b1 = bfc[16 + col];
    #pragma unroll
    for (int r = 0; r < 4; ++r) {
        int m = m0 + quad * 4 + r;
        sc[(size_t)m * 32 + col] = C0[r] + b0;
        sc[(size_t)m * 32 + 16 + col] = C1[r] + b1;
    }
}

// ---------------- CRF: true path score + forward algorithm, loss += total - true ----------------
// Double-buffered alpha: ONE barrier per t-step; sc/mask prefetched one step ahead.
__global__ __launch_bounds__(1024, 1) void k_crf(const float* __restrict__ sc, const int* __restrict__ tags,
                                                 const int* __restrict__ mask, const float* __restrict__ tr,
                                                 float* __restrict__ out) {
    __shared__ float Tm[32][33];
    __shared__ float al[2][32];
    __shared__ float trueb;
    const int b = blockIdx.x, tid = threadIdx.x;
    { int i = tid >> 5, j = tid & 31; Tm[i][j] = tr[tid]; }
    __syncthreads();
    if (tid < 64) {
        float acc = 0.f; int cnt = 0;
        for (int t = tid; t < 512; t += 64) cnt += mask[b * 512 + t];
        for (int t = tid + 1; t < 512; t += 64) {
            if (mask[b * 512 + t]) {
                int tg = tags[b * 512 + t], tp = tags[b * 512 + t - 1];
                acc += Tm[tp][tg] + sc[((size_t)t * 64 + b) * 32 + tg];
            }
        }
        #pragma unroll
        for (int m = 1; m < 64; m <<= 1) { acc += __shfl_xor(acc, m); cnt += __shfl_xor(cnt, m); }
        if (tid == 0) {
            int tg0 = tags[b * 512];
            float first = Tm[30][tg0] + sc[(size_t)b * 32 + tg0];
            int lt = tags[b * 512 + cnt - 1];
            trueb = first + acc + Tm[lt][31];
        }
    }
    if (tid < 32) al[0][tid] = Tm[30][tid] + sc[(size_t)b * 32 + tid];
    __syncthreads();
    const int j = tid >> 5, i = tid & 31;
    int cur = 0;
    float scn = sc[((size_t)64 + b) * 32 + j];
    int mkn = mask[b * 512 + 1];
    #pragma clang loop unroll(disable)
    for (int t = 1; t < 512; ++t) {
        float v = al[cur][i] + Tm[i][j];
        float mx = v;
        #pragma unroll
        for (int m = 1; m < 32; m <<= 1) mx = fmaxf(mx, __shfl_xor(mx, m));
        float e = __expf(v - mx);
        #pragma unroll
        for (int m = 1; m < 32; m <<= 1) e += __shfl_xor(e, m);
        float nv = mx + __logf(e) + scn;
        int mk = mkn;
        int tn = t < 511 ? t + 1 : 511;
        scn = sc[((size_t)tn * 64 + b) * 32 + j];
        mkn = mask[b * 512 + tn];
        if (i == 0) al[cur ^ 1][j] = mk ? nv : al[cur][j];
        __syncthreads();
        cur ^= 1;
    }
    if (tid < 32) {
        float v = al[cur][tid] + Tm[tid][31];
        float mx = v;
        #pragma unroll
        for (int m = 1; m < 32; m <<= 1) mx = fmaxf(mx, __shfl_xor(mx, m));
        float e = __expf(v - mx);
        #pragma unroll
        for (int m = 1; m < 32; m <<= 1) e += __shfl_xor(e, m);
        if (tid == 0) atomicAdd(out, mx + __logf(e) - trueb);
    }
}

extern "C" void kernel_launch(void* const* d_in, const int* in_sizes, int n_in,
                              void* d_out, int out_size, void* d_ws, size_t ws_size,
                              hipStream_t stream) {
    const int* x      = (const int*)d_in[0];
    const int* tags   = (const int*)d_in[1];
    const int* mask   = (const int*)d_in[2];
    const float* emb  = (const float*)d_in[3];
    const float* wihf = (const float*)d_in[4];
    const float* whhf = (const float*)d_in[5];
    const float* bf_  = (const float*)d_in[6];
    const float* wihb = (const float*)d_in[7];
    const float* whhb = (const float*)d_in[8];
    const float* bb_  = (const float*)d_in[9];
    const float* wfc  = (const float*)d_in[10];
    const float* bfc  = (const float*)d_in[11];
    const float* tr   = (const float*)d_in[12];

    char* ws = (char*)d_ws;
    unsigned short* et   = (unsigned short*)(ws);                 //  16,777,216 B
    unsigned short* wbf  = (unsigned short*)(ws + 16777216);      //   1,064,960 B (wih f|b cat, then wfc @ elem 524288)
    unsigned char*  w8   = (unsigned char*)(ws + 17842176);      //     524,288 B (whh f|b fp8)
    unsigned short* gx   = (unsigned short*)(ws + 18366464);      // 134,217,728 B
    unsigned short* hcat = (unsigned short*)(ws + 152584192);     //  33,554,432 B
    float* sc            = (float*)(ws + 186138624);              //   4,194,304 B

    hipMemsetAsync(d_out, 0, sizeof(float), stream);
    k_cast_weights<<<2080, 256, 0, stream>>>(wihf, wihb, wfc, wbf);
    k_cast_fp8<<<1024, 256, 0, stream>>>(whhf, whhb, w8);
    k_gather<<<4096, 256, 0, stream>>>(x, emb, et);
    dim3 g2(256, 16);
    k_gx<<<g2, 256, 0, stream>>>(et, wbf, bf_, bb_, gx);
    k_lstm<<<64, 512, 0, stream>>>(w8, gx, hcat);
    k_scores<<<512, 256, 0, stream>>>(hcat, wbf + 524288, bfc, sc);
    k_crf<<<64, 1024, 0, stream>>>(sc, tags, mask, tr, (float*)d_out);
}